// Round 7
// baseline (21134.294 us; speedup 1.0000x reference)
//
#include <hip/hip_runtime.h>

typedef unsigned short u16;
typedef unsigned int u32;
typedef unsigned long long u64;
typedef __attribute__((ext_vector_type(8))) short bf16x8;
typedef __attribute__((ext_vector_type(8))) unsigned short u16x8;
typedef __attribute__((ext_vector_type(4))) unsigned short u16x4;
typedef __attribute__((ext_vector_type(4))) float f32x4;

#define DEVI static __device__ __forceinline__
#define MFMA __builtin_amdgcn_mfma_f32_16x16x32_bf16

constexpr int B = 32, S = 128, T = 64, H = 512, V = 32000;
constexpr int H4 = 4 * H;          // 2048
constexpr int TD = T - 1;          // 63 decoder steps
constexpr int MOUT = TD * B;       // 2016
constexpr int KOUT = 3 * H;        // 1536
constexpr int PAD_IDX = 1;

DEVI u16 f2bf(float f) {
  union { float f; unsigned u; } v; v.f = f;
  unsigned r = (v.u + 0x7fffu + ((v.u >> 16) & 1u)) >> 16;
  return (u16)r;
}
DEVI float bf2f(u16 h) {
  union { unsigned u; float f; } v; v.u = ((unsigned)h) << 16;
  return v.f;
}
DEVI float sigm(float x) { return 1.f / (1.f + __expf(-x)); }
DEVI float tanh_(float x) {
  float ax = fabsf(x);
  float e = __expf(-2.f * ax);
  float t = (1.f - e) / (1.f + e);
  return x < 0.f ? -t : t;
}
DEVI int swz(int row, int k8) { return row * 32 + ((k8 ^ (row & 3)) << 3); }

// ---------------- bf16 MFMA GEMM:  C[M,N] = A[M,K] * Bt[N,K]^T + bias ------
__global__ __launch_bounds__(256) void gemm_bt(
    const u16* __restrict__ A, int lda,
    const u16* __restrict__ Bt, int ldb,
    float* __restrict__ C, int ldc,
    const float* __restrict__ bias, int M, int K, int bf16out) {
  __shared__ u16 As[128 * 32], Bs[128 * 32];
  const int tid = threadIdx.x;
  const int m0 = blockIdx.y * 128, n0 = blockIdx.x * 128;
  const int lane = tid & 63, w = tid >> 6, wm = w >> 1, wn = w & 1;
  const int lr = lane & 15, lk = lane >> 4;
  f32x4 acc[4][4] = {};
  const int r = tid >> 1, cc = (tid & 1) * 16, k8b = (tid & 1) * 2;

  for (int k0 = 0; k0 < K; k0 += 32) {
    {
      long gr = m0 + r;
      u16x8 v0 = {}, v1 = {};
      if (gr < M) {
        const u16* s = A + gr * (long)lda + k0 + cc;
        v0 = *(const u16x8*)s;
        v1 = *(const u16x8*)(s + 8);
      }
      *(u16x8*)&As[swz(r, k8b)] = v0;
      *(u16x8*)&As[swz(r, k8b + 1)] = v1;
    }
    {
      const u16* s = Bt + (long)(n0 + r) * ldb + k0 + cc;
      u16x8 v0 = *(const u16x8*)s;
      u16x8 v1 = *(const u16x8*)(s + 8);
      *(u16x8*)&Bs[swz(r, k8b)] = v0;
      *(u16x8*)&Bs[swz(r, k8b + 1)] = v1;
    }
    __syncthreads();
    bf16x8 af[4], bfr[4];
#pragma unroll
    for (int mi = 0; mi < 4; mi++)
      af[mi] = *(const bf16x8*)&As[swz(wm * 64 + mi * 16 + lr, lk)];
#pragma unroll
    for (int ni = 0; ni < 4; ni++)
      bfr[ni] = *(const bf16x8*)&Bs[swz(wn * 64 + ni * 16 + lr, lk)];
#pragma unroll
    for (int mi = 0; mi < 4; mi++)
#pragma unroll
      for (int ni = 0; ni < 4; ni++)
        acc[mi][ni] = MFMA(af[mi], bfr[ni], acc[mi][ni], 0, 0, 0);
    __syncthreads();
  }
#pragma unroll
  for (int ni = 0; ni < 4; ni++) {
    int col = n0 + wn * 64 + ni * 16 + lr;
    float bs = bias ? bias[col] : 0.f;
#pragma unroll
    for (int mi = 0; mi < 4; mi++) {
#pragma unroll
      for (int rr = 0; rr < 4; rr++) {
        long row = m0 + wm * 64 + mi * 16 + lk * 4 + rr;
        if (row < M) {
          float v = acc[mi][ni][rr] + bs;
          if (bf16out)
            ((u16*)C)[row * (long)ldc + col] = f2bf(v);
          else
            C[row * (long)ldc + col] = v;
        }
      }
    }
  }
}

// ---------------- helpers ---------------------------------------------------
__global__ void zero_f(float* p, long n) {
  long i = (long)blockIdx.x * 256 + threadIdx.x;
  long st = (long)gridDim.x * 256;
  for (; i < n; i += st) p[i] = 0.f;
}

__global__ void cast_bf(const float* __restrict__ src, u16* __restrict__ dst,
                        int ld, int off, int Csz) {
  long row = blockIdx.y;
  int col = blockIdx.x * 256 + threadIdx.x;
  dst[row * Csz + col] = f2bf(src[row * ld + off + col]);
}

__global__ void cast_bf4(const float* __restrict__ src, u16* __restrict__ dst,
                         long n4) {
  long i = (long)blockIdx.x * 256 + threadIdx.x;
  if (i >= n4) return;
  float4 v = ((const float4*)src)[i];
  u16x4 o;
  o[0] = f2bf(v.x); o[1] = f2bf(v.y); o[2] = f2bf(v.z); o[3] = f2bf(v.w);
  *(u16x4*)&dst[i * 4] = o;
}

__global__ void bias_sum(const float* __restrict__ a,
                         const float* __restrict__ b, float* __restrict__ o) {
  int i = blockIdx.x * 256 + threadIdx.x;
  o[i] = a[i] + b[i];
}

// wdec[n][0:512] = dec_wih[n][512:1024]; wdec[n][512:1024] = dec_whh[n][:]
__global__ void pack_wdec(const float* __restrict__ wih,
                          const float* __restrict__ whh, u16* __restrict__ dst) {
  int n = blockIdx.y;
  int c = blockIdx.x * 256 + threadIdx.x;
  float v = (c < 512) ? wih[(size_t)n * 1024 + 512 + c]
                      : whh[(size_t)n * 512 + (c - 512)];
  dst[(size_t)n * 1024 + c] = f2bf(v);
}

__global__ void gather_src_emb(const int* __restrict__ src,
                               const float* __restrict__ emb,
                               u16* __restrict__ dst) {
  int row = blockIdx.y;           // row = t*B + b
  int t = row >> 5, b = row & 31;
  int c = blockIdx.x * 256 + threadIdx.x;
  int tok = src[b * S + t];
  dst[(long)row * H + c] = f2bf(emb[(long)tok * H + c]);
}

__global__ void gather_trg_emb(const int* __restrict__ trg,
                               const float* __restrict__ emb,
                               u16* __restrict__ xout) {
  int row = blockIdx.y;           // row = t*B + b, t < 63
  int t = row >> 5, b = row & 31;
  int c = blockIdx.x * 256 + threadIdx.x;
  int tok = trg[b * T + t];
  xout[(long)row * KOUT + 2 * H + c] = f2bf(emb[(long)tok * H + c]);
}

// ---------------- fused per-batch persistent RNN ----------------------------
// 16 blocks x 512 threads; block bk owns batches 2bk, 2bk+1. Zero inter-block
// communication. In-loop weights streamed from L2 as MFMA B-fragments
// (2 blocks/XCD share the L2-resident lines). M=2 MFMAs via lane&1 A-rows.
__global__ __launch_bounds__(512) void rnn_fused(
    const u16* __restrict__ wenc_bf,   // enc_whh bf16 [2048][512]
    const float* __restrict__ xih,     // [S*B][2048] f32, benc folded
    const u16* __restrict__ fcw_bf,    // [512][512]
    const float* __restrict__ fc_b,
    const u16* __restrict__ a1_bf,     // attn_w[:, :512] bf16
    const u16* __restrict__ w2_bf,     // attn_w[:, 512:] bf16
    const float* __restrict__ attn_b, const float* __restrict__ attn_v,
    const int* __restrict__ src,
    const u16* __restrict__ wdec_bf,   // [2048][1024] = [W_w | W_h]
    const float* __restrict__ eih,     // [TD*B][2048] f32, bdec folded
    u16* __restrict__ enc_bt_bf,       // [B][S][512]
    u16* __restrict__ enc_btT_bf,      // [B][512][S]
    u16* __restrict__ epart_bf,        // [B][S][512], scaled by 2*log2(e)
    u16* __restrict__ xout_bf) {       // [TD*B][1536]
  const int tid = threadIdx.x, bk = blockIdx.x;
  const int wave = tid >> 6, lane = tid & 63;
  const int lr = lane & 15, lk = lane >> 4;
  const int b0 = bk * 2;
  const float L2E2 = 2.88539008f;   // 2*log2(e)
  const float L2E = 1.44269504f;

  __shared__ u16 hs2[2][1024];      // [b][0:512]=weighted, [512:1024]=h
  __shared__ float gates_s[2][2048];
  __shared__ float hp_s[2][512];
  __shared__ float sc_s[2][128];
  __shared__ u16 p_s[2][128];
  __shared__ int smask_s[2][128];
  __shared__ float red_s[8];

  float c_r0 = 0.f, c_r1 = 0.f;
  for (int i = tid; i < 2048; i += 512) ((u16*)hs2)[i] = 0;
  if (tid < 256)
    smask_s[tid >> 7][tid & 127] = src[(b0 + (tid >> 7)) * S + (tid & 127)];
  float n2v8[8];
#pragma unroll
  for (int e = 0; e < 8; e++) n2v8[e] = -2.f * attn_v[lane * 8 + e];
  if (wave == 0) {
    float sv = 0.f;
#pragma unroll
    for (int e = 0; e < 8; e++) sv += attn_v[lane * 8 + e];
#pragma unroll
    for (int o = 32; o; o >>= 1) sv += __shfl_xor(sv, o);
    if (lane == 0) red_s[4] = sv;
  }
  __syncthreads();

  // ===== encoder =====
  for (int t = 0; t < S; t++) {
    float xg0[4], xg1[4];
#pragma unroll
    for (int g = 0; g < 4; g++) {
      xg0[g] = xih[((size_t)t * B + b0) * H4 + g * H + tid];
      xg1[g] = xih[((size_t)t * B + b0 + 1) * H4 + g * H + tid];
    }
    for (int ni = 0; ni < 16; ni++) {
      int n0 = (wave * 16 + ni) * 16;
      f32x4 acc = {};
#pragma unroll
      for (int kt = 0; kt < 16; kt++) {
        bf16x8 a = *(const bf16x8*)&hs2[lr & 1][512 + kt * 32 + lk * 8];
        bf16x8 b = *(const bf16x8*)(wenc_bf + (size_t)(n0 + lr) * 512 +
                                    kt * 32 + lk * 8);
        acc = MFMA(a, b, acc, 0, 0, 0);
      }
      if (lane < 16) {
        gates_s[0][n0 + lr] = acc[0];
        gates_s[1][n0 + lr] = acc[1];
      }
    }
    __syncthreads();
    {
      float gi = xg0[0] + gates_s[0][tid];
      float gf = xg0[1] + gates_s[0][512 + tid];
      float gg = xg0[2] + gates_s[0][1024 + tid];
      float go = xg0[3] + gates_s[0][1536 + tid];
      float cn = sigm(gf) * c_r0 + sigm(gi) * tanh_(gg);
      c_r0 = cn;
      u16 h16 = f2bf(sigm(go) * tanh_(cn));
      hs2[0][512 + tid] = h16;
      enc_bt_bf[((size_t)b0 * S + t) * H + tid] = h16;
      gi = xg1[0] + gates_s[1][tid];
      gf = xg1[1] + gates_s[1][512 + tid];
      gg = xg1[2] + gates_s[1][1024 + tid];
      go = xg1[3] + gates_s[1][1536 + tid];
      cn = sigm(gf) * c_r1 + sigm(gi) * tanh_(gg);
      c_r1 = cn;
      h16 = f2bf(sigm(go) * tanh_(cn));
      hs2[1][512 + tid] = h16;
      enc_bt_bf[((size_t)(b0 + 1) * S + t) * H + tid] = h16;
    }
    __syncthreads();
  }

  // ===== fc: hidden = tanh(hf @ fc_w^T + fc_b) =====
  {
    f32x4 acc4[4];
    for (int ni = 0; ni < 4; ni++) {
      int n0 = (wave * 4 + ni) * 16;
      f32x4 acc = {};
#pragma unroll
      for (int kt = 0; kt < 16; kt++) {
        bf16x8 a = *(const bf16x8*)&hs2[lr & 1][512 + kt * 32 + lk * 8];
        bf16x8 b = *(const bf16x8*)(fcw_bf + (size_t)(n0 + lr) * 512 +
                                    kt * 32 + lk * 8);
        acc = MFMA(a, b, acc, 0, 0, 0);
      }
      acc4[ni] = acc;
    }
    __syncthreads();
    for (int ni = 0; ni < 4; ni++) {
      int n0 = (wave * 4 + ni) * 16;
      if (lane < 16) {
        float bs = fc_b[n0 + lr];
        hs2[0][512 + n0 + lr] = f2bf(tanh_(acc4[ni][0] + bs));
        hs2[1][512 + n0 + lr] = f2bf(tanh_(acc4[ni][1] + bs));
      }
    }
    __syncthreads();
  }

  // ===== transpose enc_bt -> enc_btT =====
  for (int bb = 0; bb < 2; bb++) {
    const u16* rb = enc_bt_bf + (size_t)(b0 + bb) * S * H;
    u16* wb = enc_btT_bf + (size_t)(b0 + bb) * H * S;
    for (int s8 = 0; s8 < S; s8 += 8) {
      u16x8 v;
#pragma unroll
      for (int e = 0; e < 8; e++) v[e] = rb[(size_t)(s8 + e) * H + tid];
      *(u16x8*)&wb[(size_t)tid * S + s8] = v;
    }
  }
  // ===== epart = (enc_bt @ W2^T + attn_b) * 2log2e =====
  for (int idx = wave; idx < 512; idx += 8) {
    int mt = idx >> 5, nt = idx & 31;
    f32x4 acc = {};
#pragma unroll
    for (int kt = 0; kt < 16; kt++) {
      bf16x8 a = *(const bf16x8*)(enc_bt_bf +
                                  ((size_t)b0 * S + mt * 16 + lr) * H +
                                  kt * 32 + lk * 8);
      bf16x8 b = *(const bf16x8*)(w2_bf + (size_t)(nt * 16 + lr) * 512 +
                                  kt * 32 + lk * 8);
      acc = MFMA(a, b, acc, 0, 0, 0);
    }
    int col = nt * 16 + lr;
    float bs = attn_b[col];
#pragma unroll
    for (int reg = 0; reg < 4; reg++) {
      int m = mt * 16 + lk * 4 + reg;
      epart_bf[((size_t)b0 * S + m) * H + col] = f2bf((acc[reg] + bs) * L2E2);
    }
  }
  __syncthreads();

  // ===== decoder =====
  for (int t = 0; t < TD; t++) {
    float eg0[4], eg1[4];
#pragma unroll
    for (int g = 0; g < 4; g++) {
      eg0[g] = eih[((size_t)t * B + b0) * H4 + g * H + tid];
      eg1[g] = eih[((size_t)t * B + b0 + 1) * H4 + g * H + tid];
    }
    // P0: hp = (h @ a1^T) * 2log2e
    for (int ni = 0; ni < 4; ni++) {
      int n0 = (wave * 4 + ni) * 16;
      f32x4 acc = {};
#pragma unroll
      for (int kt = 0; kt < 16; kt++) {
        bf16x8 a = *(const bf16x8*)&hs2[lr & 1][512 + kt * 32 + lk * 8];
        bf16x8 b = *(const bf16x8*)(a1_bf + (size_t)(n0 + lr) * 512 +
                                    kt * 32 + lk * 8);
        acc = MFMA(a, b, acc, 0, 0, 0);
      }
      if (lane < 16) {
        hp_s[0][n0 + lr] = acc[0] * L2E2;
        hp_s[1][n0 + lr] = acc[1] * L2E2;
      }
    }
    __syncthreads();
    // P1: scores
    {
      float hp80[8], hp81[8];
#pragma unroll
      for (int e = 0; e < 8; e++) {
        hp80[e] = hp_s[0][lane * 8 + e];
        hp81[e] = hp_s[1][lane * 8 + e];
      }
      float SV = red_s[4];
      for (int i = 0; i < 32; i++) {
        int d = wave * 32 + i;
        int bb = d >> 7, s = d & 127;
        const float* hp8 = bb ? hp81 : hp80;
        u16x8 e8 = *(const u16x8*)&epart_bf[((size_t)(b0 + bb) * S + s) * H +
                                            lane * 8];
        float a = 0.f;
#pragma unroll
        for (int e = 0; e < 8; e++) {
          float y = hp8[e] + bf2f(e8[e]);
          float ex = exp2f(y);
          float r = __builtin_amdgcn_rcpf(ex + 1.f);
          a = __builtin_fmaf(n2v8[e], r, a);
        }
#pragma unroll
        for (int o = 32; o; o >>= 1) a += __shfl_xor(a, o);
        if (lane == 0)
          sc_s[bb][s] = (smask_s[bb][s] == PAD_IDX) ? -1e10f : (SV + a);
      }
    }
    __syncthreads();
    // P2: softmax -> p_s (bf16)
    if (wave < 2) {
      float v = fmaxf(sc_s[wave][lane], sc_s[wave][lane + 64]);
#pragma unroll
      for (int o = 32; o; o >>= 1) v = fmaxf(v, __shfl_xor(v, o));
      if (lane == 0) red_s[wave] = v;
    }
    __syncthreads();
    if (tid < 256) {
      int bb = tid >> 7, s = tid & 127;
      sc_s[bb][s] = exp2f((sc_s[bb][s] - red_s[bb]) * L2E);
    }
    __syncthreads();
    if (wave < 2) {
      float v = sc_s[wave][lane] + sc_s[wave][lane + 64];
#pragma unroll
      for (int o = 32; o; o >>= 1) v += __shfl_xor(v, o);
      if (lane == 0) red_s[2 + wave] = 1.f / v;
    }
    __syncthreads();
    if (tid < 256) {
      int bb = tid >> 7, s = tid & 127;
      p_s[bb][s] = f2bf(sc_s[bb][s] * red_s[2 + bb]);
    }
    __syncthreads();
    // P3: weighted = p @ enc_bt (per batch, broadcast-A MFMA)
    for (int jj = 0; jj < 8; jj++) {
      int job = wave * 8 + jj;
      int bb = job >> 5, nt = job & 31, n0 = nt * 16;
      f32x4 acc = {};
#pragma unroll
      for (int kt = 0; kt < 4; kt++) {
        bf16x8 a = *(const bf16x8*)&p_s[bb][kt * 32 + lk * 8];
        bf16x8 b = *(const bf16x8*)(enc_btT_bf +
                                    ((size_t)(b0 + bb) * H + n0 + lr) * S +
                                    kt * 32 + lk * 8);
        acc = MFMA(a, b, acc, 0, 0, 0);
      }
      if (lane < 16) {
        u16 wv = f2bf(acc[0]);
        hs2[bb][n0 + lr] = wv;
        xout_bf[((size_t)t * B + b0 + bb) * KOUT + H + n0 + lr] = wv;
      }
    }
    __syncthreads();
    // P4: gates = [w|h] @ Wdec^T
    for (int ni = 0; ni < 16; ni++) {
      int n0 = (wave * 16 + ni) * 16;
      f32x4 acc = {};
#pragma unroll
      for (int kt = 0; kt < 32; kt++) {
        bf16x8 a = *(const bf16x8*)&hs2[lr & 1][kt * 32 + lk * 8];
        bf16x8 b = *(const bf16x8*)(wdec_bf + (size_t)(n0 + lr) * 1024 +
                                    kt * 32 + lk * 8);
        acc = MFMA(a, b, acc, 0, 0, 0);
      }
      if (lane < 16) {
        gates_s[0][n0 + lr] = acc[0];
        gates_s[1][n0 + lr] = acc[1];
      }
    }
    __syncthreads();
    // P5: pointwise
    {
      float gi = eg0[0] + gates_s[0][tid];
      float gf = eg0[1] + gates_s[0][512 + tid];
      float gg = eg0[2] + gates_s[0][1024 + tid];
      float go = eg0[3] + gates_s[0][1536 + tid];
      float cn = sigm(gf) * c_r0 + sigm(gi) * tanh_(gg);
      c_r0 = cn;
      u16 h16 = f2bf(sigm(go) * tanh_(cn));
      hs2[0][512 + tid] = h16;
      xout_bf[((size_t)t * B + b0) * KOUT + tid] = h16;
      gi = eg1[0] + gates_s[1][tid];
      gf = eg1[1] + gates_s[1][512 + tid];
      gg = eg1[2] + gates_s[1][1024 + tid];
      go = eg1[3] + gates_s[1][1536 + tid];
      cn = sigm(gf) * c_r1 + sigm(gi) * tanh_(gg);
      c_r1 = cn;
      h16 = f2bf(sigm(go) * tanh_(cn));
      hs2[1][512 + tid] = h16;
      xout_bf[((size_t)t * B + b0 + 1) * KOUT + tid] = h16;
    }
    __syncthreads();
  }
}

// ---------------------------------------------------------------------------
extern "C" void kernel_launch(void* const* d_in, const int* in_sizes, int n_in,
                              void* d_out, int out_size, void* d_ws,
                              size_t ws_size, hipStream_t stream) {
  const int* src = (const int*)d_in[0];
  const int* trg = (const int*)d_in[2];
  const float* enc_emb = (const float*)d_in[3];
  const float* enc_wih = (const float*)d_in[4];
  const float* enc_whh = (const float*)d_in[5];
  const float* enc_bih = (const float*)d_in[6];
  const float* enc_bhh = (const float*)d_in[7];
  const float* fc_w = (const float*)d_in[8];
  const float* fc_b = (const float*)d_in[9];
  const float* dec_emb = (const float*)d_in[10];
  const float* attn_w = (const float*)d_in[11];
  const float* attn_b = (const float*)d_in[12];
  const float* attn_v = (const float*)d_in[13];
  const float* dec_wih = (const float*)d_in[14];
  const float* dec_whh = (const float*)d_in[15];
  const float* dec_bih = (const float*)d_in[16];
  const float* dec_bhh = (const float*)d_in[17];
  const float* out_w = (const float*)d_in[18];
  const float* out_b = (const float*)d_in[19];
  float* out = (float*)d_out;

  char* wp = (char*)d_ws;
  auto alloc = [&](size_t n) {
    char* p = wp;
    wp += (n + 255) & ~(size_t)255;
    return p;
  };
  u16* outw_bf = (u16*)alloc((size_t)V * KOUT * 2);        // 98.3 MB
  u16* wencih_bf = (u16*)alloc((size_t)H4 * H * 2);        // enc_wih bf16
  u16* wenc_bf = (u16*)alloc((size_t)H4 * H * 2);          // enc_whh bf16
  u16* wdec_bf = (u16*)alloc((size_t)H4 * 2 * H * 2);      // 8.4 MB
  u16* wihE_bf = (u16*)alloc((size_t)H4 * H * 2);          // dec_wih e-part
  u16* a1_bf = (u16*)alloc((size_t)H * H * 2);
  u16* w2_bf = (u16*)alloc((size_t)H * H * 2);
  u16* fcw_bf = (u16*)alloc((size_t)H * H * 2);
  u16* xemb_bf = (u16*)alloc((size_t)S * B * H * 2);       // 4.2 MB
  float* xih = (float*)alloc((size_t)S * B * H4 * 4);      // 33.6 MB
  float* eih = (float*)alloc((size_t)MOUT * H4 * 4);       // 16.5 MB
  u16* enc_bt_bf = (u16*)alloc((size_t)B * S * H * 2);     // 4.2 MB
  u16* enc_btT_bf = (u16*)alloc((size_t)B * H * S * 2);    // 4.2 MB
  u16* epart_bf = (u16*)alloc((size_t)B * S * H * 2);      // 4.2 MB
  u16* xout_bf = (u16*)alloc((size_t)MOUT * KOUT * 2);     // 6.2 MB
  float* benc = (float*)alloc((size_t)H4 * 4);
  float* bdec = (float*)alloc((size_t)H4 * 4);

  dim3 blk(256);
  zero_f<<<dim3(256), blk, 0, stream>>>(out, (long)B * V);
  // weight prep
  cast_bf4<<<dim3(((long)V * KOUT / 4 + 255) / 256), blk, 0, stream>>>(
      out_w, outw_bf, (long)V * KOUT / 4);
  cast_bf4<<<dim3((long)H4 * H / 4 / 256), blk, 0, stream>>>(
      enc_wih, wencih_bf, (long)H4 * H / 4);
  cast_bf4<<<dim3((long)H4 * H / 4 / 256), blk, 0, stream>>>(
      enc_whh, wenc_bf, (long)H4 * H / 4);
  pack_wdec<<<dim3(4, H4), blk, 0, stream>>>(dec_wih, dec_whh, wdec_bf);
  cast_bf<<<dim3(H / 256, H4), blk, 0, stream>>>(dec_wih, wihE_bf, 2 * H, 0, H);
  cast_bf<<<dim3(H / 256, H), blk, 0, stream>>>(attn_w, a1_bf, 2 * H, 0, H);
  cast_bf<<<dim3(H / 256, H), blk, 0, stream>>>(attn_w, w2_bf, 2 * H, H, H);
  cast_bf4<<<dim3((long)H * H / 4 / 256), blk, 0, stream>>>(fc_w, fcw_bf,
                                                            (long)H * H / 4);
  bias_sum<<<dim3(H4 / 256), blk, 0, stream>>>(enc_bih, enc_bhh, benc);
  bias_sum<<<dim3(H4 / 256), blk, 0, stream>>>(dec_bih, dec_bhh, bdec);
  gather_src_emb<<<dim3(H / 256, S * B), blk, 0, stream>>>(src, enc_emb,
                                                           xemb_bf);
  gather_trg_emb<<<dim3(H / 256, MOUT), blk, 0, stream>>>(trg, dec_emb,
                                                          xout_bf);
  // input-side GEMMs (biases folded)
  gemm_bt<<<dim3(H4 / 128, (S * B) / 128), blk, 0, stream>>>(
      xemb_bf, H, wencih_bf, H, xih, H4, benc, S * B, H, 0);
  gemm_bt<<<dim3(H4 / 128, (MOUT + 127) / 128), blk, 0, stream>>>(
      xout_bf + 2 * H, KOUT, wihE_bf, H, eih, H4, bdec, MOUT, H, 0);
  // fused persistent RNN: 16 blocks, zero inter-block sync
  rnn_fused<<<dim3(16), dim3(512), 0, stream>>>(
      wenc_bf, xih, fcw_bf, fc_b, a1_bf, w2_bf, attn_b, attn_v, src, wdec_bf,
      eih, enc_bt_bf, enc_btT_bf, epart_bf, xout_bf);
  // final logits GEMM
  gemm_bt<<<dim3(V / 128, (MOUT + 127) / 128), blk, 0, stream>>>(
      xout_bf, KOUT, outw_bf, KOUT, out + (size_t)B * V, V, out_b, MOUT, KOUT,
      0);
}

// Round 8
// 3522.468 us; speedup vs baseline: 5.9999x; 5.9999x over previous
//
#include <hip/hip_runtime.h>

typedef unsigned short u16;
typedef unsigned int u32;
typedef unsigned long long u64;
typedef __attribute__((ext_vector_type(8))) short bf16x8;
typedef __attribute__((ext_vector_type(8))) unsigned short u16x8;
typedef __attribute__((ext_vector_type(4))) unsigned short u16x4;
typedef __attribute__((ext_vector_type(4))) float f32x4;

#define DEVI static __device__ __forceinline__
#define MFMA __builtin_amdgcn_mfma_f32_16x16x32_bf16

constexpr int B = 32, S = 128, T = 64, H = 512, V = 32000;
constexpr int H4 = 4 * H;          // 2048
constexpr int TD = T - 1;          // 63 decoder steps
constexpr int MOUT = TD * B;       // 2016
constexpr int KOUT = 3 * H;        // 1536
constexpr int PAD_IDX = 1;

DEVI u16 f2bf(float f) {
  union { float f; unsigned u; } v; v.f = f;
  unsigned r = (v.u + 0x7fffu + ((v.u >> 16) & 1u)) >> 16;
  return (u16)r;
}
DEVI float bf2f(u16 h) {
  union { unsigned u; float f; } v; v.u = ((unsigned)h) << 16;
  return v.f;
}
DEVI float sigm(float x) { return 1.f / (1.f + __expf(-x)); }
DEVI float tanh_(float x) {
  float ax = fabsf(x);
  float e = __expf(-2.f * ax);
  float t = (1.f - e) / (1.f + e);
  return x < 0.f ? -t : t;
}
DEVI float tanhf_(float x) {
  float e = __expf(2.f * x);
  return 1.f - 2.f * __builtin_amdgcn_rcpf(e + 1.f);
}
DEVI int swz(int row, int k8) { return row * 32 + ((k8 ^ (row & 3)) << 3); }

DEVI u64 pack4u(const u16* p) {
  return (u64)p[0] | ((u64)p[1] << 16) | ((u64)p[2] << 32) | ((u64)p[3] << 48);
}
// data write-through to coherence point; returned old keeps vmcnt honest
DEVI u64 xstore(u16* p, u64 v) {
  return __hip_atomic_exchange((u64*)p, v, __ATOMIC_RELAXED,
                               __HIP_MEMORY_SCOPE_AGENT);
}
DEVI void sstore(unsigned* p, unsigned v) {
  __hip_atomic_exchange(p, v, __ATOMIC_RELAXED, __HIP_MEMORY_SCOPE_AGENT);
}
// poll with exponential backoff: 4 tight iterations, then ~0.2us naps
DEVI void poll_bo(unsigned* p, unsigned tgt) {
  int it = 0;
  long long t0 = (long long)__builtin_amdgcn_s_memrealtime();
  while (__hip_atomic_load(p, __ATOMIC_RELAXED, __HIP_MEMORY_SCOPE_AGENT) <
         tgt) {
    if (it < 4) {
      __builtin_amdgcn_s_sleep(1);
      it++;
    } else {
      __builtin_amdgcn_s_sleep(8);
    }
    if ((long long)__builtin_amdgcn_s_memrealtime() - t0 > 20000000ll) break;
  }
}

// ---------------- bf16 MFMA GEMM:  C[M,N] = A[M,K] * Bt[N,K]^T + bias ------
// outmode: 0 = f32 row-major; 1 = bf16 row-major; 2 = bf16 G3-tiled
// (G3: [n/16-block bkx][b][r][s] with n = g*512 + bkx*4 + q, r = q*4+g,
//  row = b*128 + s)
__global__ __launch_bounds__(256) void gemm_bt(
    const u16* __restrict__ A, int lda,
    const u16* __restrict__ Bt, int ldb,
    float* __restrict__ C, int ldc,
    const float* __restrict__ bias, int M, int K, int outmode) {
  __shared__ u16 As[128 * 32], Bs[128 * 32];
  const int tid = threadIdx.x;
  const int m0 = blockIdx.y * 128, n0 = blockIdx.x * 128;
  const int lane = tid & 63, w = tid >> 6, wm = w >> 1, wn = w & 1;
  const int lr = lane & 15, lk = lane >> 4;
  f32x4 acc[4][4] = {};
  const int r = tid >> 1, cc = (tid & 1) * 16, k8b = (tid & 1) * 2;

  for (int k0 = 0; k0 < K; k0 += 32) {
    {
      long gr = m0 + r;
      u16x8 v0 = {}, v1 = {};
      if (gr < M) {
        const u16* s = A + gr * (long)lda + k0 + cc;
        v0 = *(const u16x8*)s;
        v1 = *(const u16x8*)(s + 8);
      }
      *(u16x8*)&As[swz(r, k8b)] = v0;
      *(u16x8*)&As[swz(r, k8b + 1)] = v1;
    }
    {
      const u16* s = Bt + (long)(n0 + r) * ldb + k0 + cc;
      u16x8 v0 = *(const u16x8*)s;
      u16x8 v1 = *(const u16x8*)(s + 8);
      *(u16x8*)&Bs[swz(r, k8b)] = v0;
      *(u16x8*)&Bs[swz(r, k8b + 1)] = v1;
    }
    __syncthreads();
    bf16x8 af[4], bfr[4];
#pragma unroll
    for (int mi = 0; mi < 4; mi++)
      af[mi] = *(const bf16x8*)&As[swz(wm * 64 + mi * 16 + lr, lk)];
#pragma unroll
    for (int ni = 0; ni < 4; ni++)
      bfr[ni] = *(const bf16x8*)&Bs[swz(wn * 64 + ni * 16 + lr, lk)];
#pragma unroll
    for (int mi = 0; mi < 4; mi++)
#pragma unroll
      for (int ni = 0; ni < 4; ni++)
        acc[mi][ni] = MFMA(af[mi], bfr[ni], acc[mi][ni], 0, 0, 0);
    __syncthreads();
  }
#pragma unroll
  for (int ni = 0; ni < 4; ni++) {
    int col = n0 + wn * 64 + ni * 16 + lr;
    float bs = bias ? bias[col] : 0.f;
#pragma unroll
    for (int mi = 0; mi < 4; mi++) {
#pragma unroll
      for (int rr = 0; rr < 4; rr++) {
        long row = m0 + wm * 64 + mi * 16 + lk * 4 + rr;
        if (row < M) {
          float v = acc[mi][ni][rr] + bs;
          if (outmode == 0) {
            C[row * (long)ldc + col] = v;
          } else if (outmode == 1) {
            ((u16*)C)[row * (long)ldc + col] = f2bf(v);
          } else {
            int g = col >> 9, jj = col & 511, bkx = jj >> 2, q = jj & 3;
            int rq = q * 4 + g;
            long b = row >> 7, s = row & 127;
            ((u16*)C)[((((size_t)bkx * 32 + b) * 16 + rq) << 7) + s] = f2bf(v);
          }
        }
      }
    }
  }
}

// ---------------- helpers ---------------------------------------------------
__global__ void zero_f(float* p, long n) {
  long i = (long)blockIdx.x * 256 + threadIdx.x;
  long st = (long)gridDim.x * 256;
  for (; i < n; i += st) p[i] = 0.f;
}

__global__ void zero_u(unsigned* p, int n) {
  int i = blockIdx.x * 256 + threadIdx.x;
  if (i < n) p[i] = 0u;
}

__global__ void cast_bf(const float* __restrict__ src, u16* __restrict__ dst,
                        int ld, int off, int Csz) {
  long row = blockIdx.y;
  int col = blockIdx.x * 256 + threadIdx.x;
  dst[row * Csz + col] = f2bf(src[row * ld + off + col]);
}

__global__ void cast_bf4(const float* __restrict__ src, u16* __restrict__ dst,
                         long n4) {
  long i = (long)blockIdx.x * 256 + threadIdx.x;
  if (i >= n4) return;
  float4 v = ((const float4*)src)[i];
  u16x4 o;
  o[0] = f2bf(v.x); o[1] = f2bf(v.y); o[2] = f2bf(v.z); o[3] = f2bf(v.w);
  *(u16x4*)&dst[i * 4] = o;
}

// permuted-row cast: dst row n' = src row (g*H + jH), n' = jH*4 + g
__global__ void cast_perm(const float* __restrict__ src, int ld, int off,
                          u16* __restrict__ dst) {
  int np = blockIdx.y;
  int c = blockIdx.x * 256 + threadIdx.x;
  int g = np & 3, jH = np >> 2;
  dst[(size_t)np * H + c] = f2bf(src[(size_t)(g * H + jH) * ld + off + c]);
}

__global__ void bias_perm(const float* __restrict__ a,
                          const float* __restrict__ b, float* __restrict__ o) {
  int np = blockIdx.x * 256 + threadIdx.x;
  int g = np & 3, jH = np >> 2;
  int r = g * H + jH;
  o[np] = a[r] + b[r];
}

// dst[c*R + r] = bf16(src[r*ld + off + c]); grid (C/32, R/32)
__global__ __launch_bounds__(256) void cast_transpose_bf(
    const float* __restrict__ src, int ld, int off, u16* __restrict__ dst,
    int R) {
  __shared__ float tile[32][33];
  int r0 = blockIdx.y * 32, c0 = blockIdx.x * 32;
  int tx = threadIdx.x & 31, ty = threadIdx.x >> 5;
#pragma unroll
  for (int i = 0; i < 32; i += 8)
    tile[ty + i][tx] = src[(long)(r0 + ty + i) * ld + off + c0 + tx];
  __syncthreads();
#pragma unroll
  for (int i = 0; i < 32; i += 8)
    dst[(long)(c0 + ty + i) * R + r0 + tx] = f2bf(tile[tx][ty + i]);
}

__global__ void gather_src_emb(const int* __restrict__ src,
                               const float* __restrict__ emb,
                               u16* __restrict__ dst) {
  int row = blockIdx.y;           // row = t*B + b
  int t = row >> 5, b = row & 31;
  int c = blockIdx.x * 256 + threadIdx.x;
  int tok = src[b * S + t];
  dst[(long)row * H + c] = f2bf(emb[(long)tok * H + c]);
}

__global__ void gather_trg_emb(const int* __restrict__ trg,
                               const float* __restrict__ emb,
                               u16* __restrict__ xout) {
  int row = blockIdx.y;           // row = t*B + b, t < 63
  int t = row >> 5, b = row & 31;
  int c = blockIdx.x * 256 + threadIdx.x;
  int tok = trg[b * T + t];
  xout[(long)row * KOUT + 2 * H + c] = f2bf(emb[(long)tok * H + c]);
}

// ---------------- persistent encoder ----------------------------------------
// 128 blocks x 128 threads. Block bk owns cols [bk*4, bk*4+4) for all gates.
__global__ __launch_bounds__(128) void enc_persist(
    unsigned* fes, const float* __restrict__ whh,
    const float* __restrict__ xih_p, u16* hstep, u16* enc_bt_bf, float* cbuf) {
  const int tid = threadIdx.x, bk = blockIdx.x;
  const int wave = tid >> 6, lane = tid & 63;
  __shared__ float gs[32][16];
  __shared__ float c_s[128];
  __shared__ u16 hx[128];
  bf16x8 wf[16];
  {
    int n = lane & 15, g = n & 3, q = n >> 2;
    const float* wrow =
        whh + ((size_t)g * H + bk * 4 + q) * H + (lane >> 4) * 8;
#pragma unroll
    for (int kt = 0; kt < 16; kt++) {
      bf16x8 f;
#pragma unroll
      for (int e = 0; e < 8; e++) f[e] = (short)f2bf(wrow[kt * 32 + e]);
      wf[kt] = f;
    }
  }
  c_s[tid] = 0.f;
  for (int t = 0; t < S; t++) {
    if (t > 0) {
      poll_bo(fes + tid * 16, (unsigned)t);
      __syncthreads();
    }
    float4 xv = *(const float4*)(xih_p + ((size_t)t * B + (tid >> 2)) * H4 +
                                 (bk * 4 + (tid & 3)) * 4);
    if (t > 0) {
      const u16* hb = hstep + (size_t)t * B * H +
                      (size_t)(wave * 16 + (lane & 15)) * H + (lane >> 4) * 8;
      f32x4 acc = {};
#pragma unroll
      for (int kt = 0; kt < 16; kt++) {
        bf16x8 a = *(const bf16x8*)(hb + kt * 32);
        acc = MFMA(a, wf[kt], acc, 0, 0, 0);
      }
      int n = lane & 15, r0 = (lane >> 4) * 4;
#pragma unroll
      for (int rr = 0; rr < 4; rr++) gs[wave * 16 + r0 + rr][n] = acc[rr];
    } else {
      int n = lane & 15, r0 = (lane >> 4) * 4;
#pragma unroll
      for (int rr = 0; rr < 4; rr++) gs[wave * 16 + r0 + rr][n] = 0.f;
    }
    __syncthreads();
    {
      int b = tid >> 2, q = tid & 3;
      float gi = xv.x + gs[b][q * 4 + 0];
      float gf = xv.y + gs[b][q * 4 + 1];
      float gg = xv.z + gs[b][q * 4 + 2];
      float go = xv.w + gs[b][q * 4 + 3];
      float cn = sigm(gf) * c_s[tid] + sigm(gi) * tanh_(gg);
      c_s[tid] = cn;
      float hn = sigm(go) * tanh_(cn);
      u16 h16 = f2bf(hn);
      hx[tid] = h16;
      enc_bt_bf[((size_t)b * S + t) * H + bk * 4 + q] = h16;
    }
    __syncthreads();
    u64 kp = 0;
    if (tid < 32)
      kp = xstore(hstep + (size_t)(t + 1) * B * H + (size_t)tid * H + bk * 4,
                  pack4u(&hx[tid * 4]));
    if (wave == 0) {
      asm volatile("" :: "v"(kp));
      asm volatile("s_waitcnt vmcnt(0)" ::: "memory");
      if (tid == 0) sstore(fes + bk * 16, (unsigned)(t + 1));
    }
  }
  {
    int b = tid >> 2, q = tid & 3;
    cbuf[b * H + bk * 4 + q] = c_s[tid];
  }
}

// ---------------- persistent decoder ----------------------------------------
// 128 blocks x 512 threads. Exchanges per step: h (col-sharded publish) and
// p (softmax weights, 256 B/batch). gates_w = p @ G3 (G3 L2-stationary).
__global__ __launch_bounds__(512) void dec_persist(
    unsigned* fhs, unsigned* fws, const float* __restrict__ fc_w,
    const float* __restrict__ fc_b, const float* __restrict__ dec_whh,
    const u16* __restrict__ a1T_bf, const float* __restrict__ attn_v,
    const int* __restrict__ src, const u16* __restrict__ hf_bf,
    const float* __restrict__ cbuf, const u16* __restrict__ epart_bf,
    const u16* __restrict__ enc_bt_bf, const u16* __restrict__ G3,
    const float* __restrict__ eih_p, u16* hstep, u16* pst,
    u16* __restrict__ xout_bf) {
  const int tid = threadIdx.x, bk = blockIdx.x;
  const int wave = tid >> 6, lane = tid & 63;
  __shared__ u16 Ws[16 * 512];      // LSTM h-part weights, XOR-swizzled (16 KB)
  __shared__ float wsum[8][H];      // hp partials / weighted partials
  __shared__ float hs[H], hps[H];
  __shared__ float gs4[2][32][16];  // gates_h k-half partials
  __shared__ float gsw[32][16];     // gates_w
  __shared__ u16 ps_s[32][128];     // softmax p for all batches
  __shared__ u16 p_l[128];
  __shared__ float sc[S], red[2];
  __shared__ int smask[S];
  __shared__ float c_s[128];
  __shared__ u16 hx[128];
  // ---- prologue: h-part LSTM weights -> LDS ----
  for (int idx = tid; idx < 16 * 512; idx += 512) {
    int n = idx >> 9, k = idx & 511;
    int g = n & 3, q = n >> 2;
    int grow = g * H + bk * 4 + q;
    Ws[n * 512 + (((k >> 3) ^ (n & 7)) << 3) + (k & 7)] =
        f2bf(dec_whh[(size_t)grow * H + k]);
  }
  if (tid < 128) c_s[tid] = cbuf[(tid >> 2) * H + bk * 4 + (tid & 3)];
  float av8[8];
  if (bk < 32) {
    if (tid < S) smask[tid] = src[bk * S + tid];
#pragma unroll
    for (int e = 0; e < 8; e++) av8[e] = attn_v[lane * 8 + e];
  }
  // fc: hidden = tanh(hf @ fc_w^T + fc_b) -> h[0]  (blocks 0..31, 16 cols)
  if (bk < 32 && wave < 2) {
    int n = lane & 15;
    const u16* hb = hf_bf + (size_t)(wave * 16 + n) * H + (lane >> 4) * 8;
    const float* frow = fc_w + (size_t)(bk * 16 + n) * H + (lane >> 4) * 8;
    f32x4 acc = {};
#pragma unroll
    for (int kt = 0; kt < 16; kt++) {
      bf16x8 a = *(const bf16x8*)(hb + kt * 32);
      bf16x8 bf;
#pragma unroll
      for (int e = 0; e < 8; e++) bf[e] = (short)f2bf(frow[kt * 32 + e]);
      acc = MFMA(a, bf, acc, 0, 0, 0);
    }
    float bias = fc_b[bk * 16 + n];
    int r0 = (lane >> 4) * 4;
#pragma unroll
    for (int rr = 0; rr < 4; rr++)
      gs4[0][wave * 16 + r0 + rr][n] = tanh_(acc[rr] + bias);
  }
  __syncthreads();
  if (bk < 32) {
    u64 kp = 0;
    if (tid < 128) {
      int b = tid >> 2, qq = tid & 3;
      u16 w0 = f2bf(gs4[0][b][qq * 4 + 0]);
      u16 w1 = f2bf(gs4[0][b][qq * 4 + 1]);
      u16 w2 = f2bf(gs4[0][b][qq * 4 + 2]);
      u16 w3 = f2bf(gs4[0][b][qq * 4 + 3]);
      u64 val = (u64)w0 | ((u64)w1 << 16) | ((u64)w2 << 32) | ((u64)w3 << 48);
      kp = xstore(hstep + (size_t)b * H + bk * 16 + qq * 4, val);
    }
    if (wave < 2) {
      asm volatile("" :: "v"(kp));
      asm volatile("s_waitcnt vmcnt(0)" ::: "memory");
    }
    __syncthreads();
    if (tid == 0) sstore(fhs + bk * 16, 1u);
  }
  // ---- time loop ----
  for (int t = 0; t < TD; t++) {
    if (tid < 128)
      poll_bo(fhs + tid * 16, (unsigned)(tid < 32 ? t + 1 : t));
    __syncthreads();
    float4 xv = {};
    if (tid < 128)
      xv = *(const float4*)(eih_p + ((size_t)t * B + (tid >> 2)) * H4 +
                            (bk * 4 + (tid & 3)) * 4);
    // phase 1: attention for batch b = bk (blocks 0..31, all 8 waves)
    if (bk < 32) {
      const int b = bk;
      if (tid < 256) {
        u32 v = ((const u32*)(hstep + (size_t)t * B * H + (size_t)b * H))[tid];
        hs[2 * tid] = bf2f((u16)(v & 0xffff));
        hs[2 * tid + 1] = bf2f((u16)(v >> 16));
      }
      __syncthreads();
      {  // hp partials: wave w covers k in [w*64, w*64+64)
        float p[8] = {};
        const int j0 = lane * 8;
#pragma unroll 4
        for (int kk = 0; kk < 64; kk++) {
          int k = wave * 64 + kk;
          float hk = hs[k];
          u16x8 av = *(const u16x8*)&a1T_bf[(size_t)k * H + j0];
#pragma unroll
          for (int e = 0; e < 8; e++) p[e] += hk * bf2f(av[e]);
        }
#pragma unroll
        for (int e = 0; e < 8; e++) wsum[wave][j0 + e] = p[e];
      }
      __syncthreads();
      {
        float s0 = 0.f;
#pragma unroll
        for (int w = 0; w < 8; w++) s0 += wsum[w][tid];
        hps[tid] = s0;
      }
      __syncthreads();
      {  // scores: wave w covers s in [w*16, w*16+16)
        const int j0 = lane * 8;
        float hp8[8];
#pragma unroll
        for (int e = 0; e < 8; e++) hp8[e] = hps[j0 + e];
        for (int i = 0; i < 16; i++) {
          int s = wave * 16 + i;
          u16x8 ep = *(const u16x8*)&epart_bf[((size_t)b * S + s) * H + j0];
          float a = 0.f;
#pragma unroll
          for (int e = 0; e < 8; e++)
            a += av8[e] * tanhf_(hp8[e] + bf2f(ep[e]));
#pragma unroll
          for (int o = 32; o; o >>= 1) a += __shfl_xor(a, o);
          if (lane == 0) sc[s] = a;
        }
      }
      __syncthreads();
      if (tid < S && smask[tid] == PAD_IDX) sc[tid] = -1e10f;
      __syncthreads();
      if (tid < 64) {
        float v = fmaxf(sc[tid], sc[tid + 64]);
#pragma unroll
        for (int o = 32; o; o >>= 1) v = fmaxf(v, __shfl_xor(v, o));
        if (tid == 0) red[0] = v;
      }
      __syncthreads();
      float mx = red[0];
      if (tid < S) sc[tid] = __expf(sc[tid] - mx);
      __syncthreads();
      if (tid < 64) {
        float v = sc[tid] + sc[tid + 64];
#pragma unroll
        for (int o = 32; o; o >>= 1) v += __shfl_xor(v, o);
        if (tid == 0) red[1] = 1.f / v;
      }
      __syncthreads();
      // publish p FIRST (unblocks all LSTM blocks), then weighted for xout
      if (tid < 128) p_l[tid] = f2bf(sc[tid] * red[1]);
      __syncthreads();
      {
        u64 kp = 0;
        if (tid < 32)
          kp = xstore(pst + ((size_t)t * B + b) * 128 + tid * 4,
                      pack4u(&p_l[tid * 4]));
        if (wave == 0) {
          asm volatile("" :: "v"(kp));
          asm volatile("s_waitcnt vmcnt(0)" ::: "memory");
          if (tid == 0) sstore(fws + bk * 16, (unsigned)(t + 1));
        }
      }
      {  // weighted partials: wave w owns s in [w*16, w*16+16)
        float acc8[8] = {};
        const int j0 = lane * 8;
        for (int i = 0; i < 16; i++) {
          int s = wave * 16 + i;
          float pscale = sc[s];
          u16x8 ev = *(const u16x8*)&enc_bt_bf[((size_t)b * S + s) * H + j0];
#pragma unroll
          for (int e = 0; e < 8; e++) acc8[e] += pscale * bf2f(ev[e]);
        }
#pragma unroll
        for (int e = 0; e < 8; e++) wsum[wave][j0 + e] = acc8[e];
      }
      __syncthreads();
      if (tid < 128) {
        float inv = red[1];
        int j0 = tid * 4;
        u16x4 o;
#pragma unroll
        for (int i = 0; i < 4; i++) {
          float wj = (wsum[0][j0 + i] + wsum[1][j0 + i] + wsum[2][j0 + i] +
                      wsum[3][j0 + i] + wsum[4][j0 + i] + wsum[5][j0 + i] +
                      wsum[6][j0 + i] + wsum[7][j0 + i]) *
                     inv;
          o[i] = f2bf(wj);
        }
        *(u16x4*)&xout_bf[((size_t)t * B + b) * KOUT + H + j0] = o;
      }
    }
    // gates_h on waves 0-3 (needs only h[t]); waves 4-7 poll + fetch p
    if (wave < 4) {
      int p = wave >> 1, sub = wave & 1;
      int m = lane & 15, ks = lane >> 4;
      const u16* hb =
          hstep + (size_t)t * B * H + (size_t)(sub * 16 + m) * H + ks * 8;
      f32x4 acc = {};
#pragma unroll
      for (int kt = p * 8; kt < p * 8 + 8; kt++) {
        bf16x8 a = *(const bf16x8*)(hb + kt * 32);
        bf16x8 w =
            *(const bf16x8*)&Ws[m * 512 + (((kt * 4 + ks) ^ (m & 7)) << 3)];
        acc = MFMA(a, w, acc, 0, 0, 0);
      }
      int r0 = ks * 4;
#pragma unroll
      for (int rr = 0; rr < 4; rr++) gs4[p][sub * 16 + r0 + rr][m] = acc[rr];
    } else {
      int i = tid - 256;            // 0..255
      int b = i >> 3, chunk = i & 7;
      poll_bo(fws + b * 16, (unsigned)(t + 1));
      const u16* pp = pst + ((size_t)t * B + b) * 128 + chunk * 16;
      u16x8 v0 = *(const u16x8*)pp;
      u16x8 v1 = *(const u16x8*)(pp + 8);
      *(u16x8*)&ps_s[b][chunk * 16] = v0;
      *(u16x8*)&ps_s[b][chunk * 16 + 8] = v1;
    }
    __syncthreads();
    // gates_w = p @ G3-slice (L2-stationary contiguous 128 KB per block)
    {
      int b = tid >> 4, rq = tid & 15;
      const u16* gp = G3 + ((((size_t)bk * 32 + b) * 16 + rq) << 7);
      float acc = 0.f;
#pragma unroll
      for (int k8 = 0; k8 < 16; k8++) {
        u16x8 g8 = *(const u16x8*)(gp + k8 * 8);
        u16x8 pp = *(const u16x8*)&ps_s[b][k8 * 8];
#pragma unroll
        for (int e = 0; e < 8; e++)
          acc = __builtin_fmaf(bf2f(pp[e]), bf2f(g8[e]), acc);
      }
      gsw[b][rq] = acc;
    }
    __syncthreads();
    // pointwise
    if (tid < 128) {
      int b2 = tid >> 2, q = tid & 3;
      float gi = xv.x + gs4[0][b2][q * 4 + 0] + gs4[1][b2][q * 4 + 0] +
                 gsw[b2][q * 4 + 0];
      float gf = xv.y + gs4[0][b2][q * 4 + 1] + gs4[1][b2][q * 4 + 1] +
                 gsw[b2][q * 4 + 1];
      float gg = xv.z + gs4[0][b2][q * 4 + 2] + gs4[1][b2][q * 4 + 2] +
                 gsw[b2][q * 4 + 2];
      float go = xv.w + gs4[0][b2][q * 4 + 3] + gs4[1][b2][q * 4 + 3] +
                 gsw[b2][q * 4 + 3];
      float cn = sigm(gf) * c_s[tid] + sigm(gi) * tanh_(gg);
      c_s[tid] = cn;
      float hn = sigm(go) * tanh_(cn);
      u16 h16 = f2bf(hn);
      hx[tid] = h16;
      xout_bf[((size_t)t * B + b2) * KOUT + bk * 4 + q] = h16;
    }
    __syncthreads();
    u64 kp2 = 0;
    if (tid < 32)
      kp2 = xstore(hstep + (size_t)(t + 1) * B * H + (size_t)tid * H + bk * 4,
                   pack4u(&hx[tid * 4]));
    if (wave == 0) {
      asm volatile("" :: "v"(kp2));
      asm volatile("s_waitcnt vmcnt(0)" ::: "memory");
      if (tid == 0)
        sstore(fhs + bk * 16, (unsigned)(bk < 32 ? t + 2 : t + 1));
    }
  }
}

// ---------------------------------------------------------------------------
extern "C" void kernel_launch(void* const* d_in, const int* in_sizes, int n_in,
                              void* d_out, int out_size, void* d_ws,
                              size_t ws_size, hipStream_t stream) {
  const int* src = (const int*)d_in[0];
  const int* trg = (const int*)d_in[2];
  const float* enc_emb = (const float*)d_in[3];
  const float* enc_wih = (const float*)d_in[4];
  const float* enc_whh = (const float*)d_in[5];
  const float* enc_bih = (const float*)d_in[6];
  const float* enc_bhh = (const float*)d_in[7];
  const float* fc_w = (const float*)d_in[8];
  const float* fc_b = (const float*)d_in[9];
  const float* dec_emb = (const float*)d_in[10];
  const float* attn_w = (const float*)d_in[11];
  const float* attn_b = (const float*)d_in[12];
  const float* attn_v = (const float*)d_in[13];
  const float* dec_wih = (const float*)d_in[14];
  const float* dec_whh = (const float*)d_in[15];
  const float* dec_bih = (const float*)d_in[16];
  const float* dec_bhh = (const float*)d_in[17];
  const float* out_w = (const float*)d_in[18];
  const float* out_b = (const float*)d_in[19];
  float* out = (float*)d_out;

  char* wp = (char*)d_ws;
  auto alloc = [&](size_t n) {
    char* p = wp;
    wp += (n + 255) & ~(size_t)255;
    return p;
  };
  u16* outw_bf = (u16*)alloc((size_t)V * KOUT * 2);        // 98.3 MB
  u16* wihenc_p = (u16*)alloc((size_t)H4 * H * 2);         // 2.1 MB
  u16* wihE_p = (u16*)alloc((size_t)H4 * H * 2);           // 2.1 MB
  u16* wihW_bf = (u16*)alloc((size_t)H4 * H * 2);          // 2.1 MB
  u16* attnw2_bf = (u16*)alloc((size_t)H * H * 2);         // 0.5 MB
  u16* a1T_bf = (u16*)alloc((size_t)H * H * 2);            // 0.5 MB
  u16* xemb_bf = (u16*)alloc((size_t)S * B * H * 2);       // 4.2 MB
  float* xih_p = (float*)alloc((size_t)S * B * H4 * 4);    // 33.6 MB
  u16* enc_bt_bf = (u16*)alloc((size_t)B * S * H * 2);     // 4.2 MB
  u16* epart_bf = (u16*)alloc((size_t)B * S * H * 2);      // 4.2 MB
  u16* G3 = (u16*)alloc((size_t)B * S * H4 * 2);           // 16.8 MB
  float* eih_p = (float*)alloc((size_t)MOUT * H4 * 4);     // 16.5 MB
  u16* xout_bf = (u16*)alloc((size_t)MOUT * KOUT * 2);     // 6.2 MB
  u16* hstep_enc = (u16*)alloc((size_t)(S + 1) * B * H * 2);  // 4.3 MB
  u16* hstep_dec = (u16*)alloc((size_t)T * B * H * 2);        // 2.1 MB
  u16* pst = (u16*)alloc((size_t)TD * B * 128 * 2);           // 0.5 MB
  float* cbuf = (float*)alloc((size_t)B * H * 4);
  float* benc_p = (float*)alloc((size_t)H4 * 4);
  float* bdec_p = (float*)alloc((size_t)H4 * 4);
  unsigned* flags = (unsigned*)alloc(4608 * 4);
  unsigned* fes = flags;            // 128 slots x 16 u32
  unsigned* fhs = flags + 2048;     // 128 slots x 16 u32
  unsigned* fws = flags + 4096;     // 32 slots x 16 u32

  dim3 blk(256);
  zero_f<<<dim3(256), blk, 0, stream>>>(out, (long)B * V);
  zero_u<<<dim3(18), blk, 0, stream>>>(flags, 4608);
  // weight preparation
  cast_bf4<<<dim3(((long)V * KOUT / 4 + 255) / 256), blk, 0, stream>>>(
      out_w, outw_bf, (long)V * KOUT / 4);
  cast_perm<<<dim3(H / 256, H4), blk, 0, stream>>>(enc_wih, H, 0, wihenc_p);
  cast_perm<<<dim3(H / 256, H4), blk, 0, stream>>>(dec_wih, 2 * H, 0, wihE_p);
  cast_bf<<<dim3(H / 256, H4), blk, 0, stream>>>(dec_wih, wihW_bf, 2 * H, H, H);
  cast_bf<<<dim3(H / 256, H), blk, 0, stream>>>(attn_w, attnw2_bf, 2 * H, H, H);
  cast_transpose_bf<<<dim3(H / 32, H / 32), blk, 0, stream>>>(attn_w, 2 * H, 0,
                                                              a1T_bf, H);
  bias_perm<<<dim3(H4 / 256), blk, 0, stream>>>(enc_bih, enc_bhh, benc_p);
  bias_perm<<<dim3(H4 / 256), blk, 0, stream>>>(dec_bih, dec_bhh, bdec_p);
  gather_src_emb<<<dim3(H / 256, S * B), blk, 0, stream>>>(src, enc_emb,
                                                           xemb_bf);
  gather_trg_emb<<<dim3(H / 256, MOUT), blk, 0, stream>>>(trg, dec_emb,
                                                          xout_bf);
  // input-side GEMMs (permuted cols, biases folded)
  gemm_bt<<<dim3(H4 / 128, (S * B) / 128), blk, 0, stream>>>(
      xemb_bf, H, wihenc_p, H, xih_p, H4, benc_p, S * B, H, 0);
  gemm_bt<<<dim3(H4 / 128, (MOUT + 127) / 128), blk, 0, stream>>>(
      xout_bf + 2 * H, KOUT, wihE_p, H, eih_p, H4, bdec_p, MOUT, H, 0);
  // persistent encoder
  enc_persist<<<dim3(128), dim3(128), 0, stream>>>(fes, enc_whh, xih_p,
                                                   hstep_enc, enc_bt_bf, cbuf);
  // epart = enc_bt @ attn_w2^T + attn_b  (bf16 out)
  gemm_bt<<<dim3(H / 128, (B * S) / 128), blk, 0, stream>>>(
      enc_bt_bf, H, attnw2_bf, H, (float*)epart_bf, H, attn_b, B * S, H, 1);
  // G3 = enc_bt @ W_w^T  (tiled bf16 out for per-block contiguous slices)
  gemm_bt<<<dim3(H4 / 128, (B * S) / 128), blk, 0, stream>>>(
      enc_bt_bf, H, wihW_bf, H, (float*)G3, H4, nullptr, B * S, H, 2);
  // persistent decoder (h_f = hstep_enc step S)
  dec_persist<<<dim3(128), dim3(512), 0, stream>>>(
      fhs, fws, fc_w, fc_b, dec_whh, a1T_bf, attn_v, src,
      hstep_enc + (size_t)S * B * H, cbuf, epart_bf, enc_bt_bf, G3, eih_p,
      hstep_dec, pst, xout_bf);
  // final logits GEMM
  gemm_bt<<<dim3(V / 128, (MOUT + 127) / 128), blk, 0, stream>>>(
      xout_bf, KOUT, outw_bf, KOUT, out + (size_t)B * V, V, out_b, MOUT, KOUT,
      0);
}

// Round 9
// 3265.149 us; speedup vs baseline: 6.4727x; 1.0788x over previous
//
#include <hip/hip_runtime.h>

typedef unsigned short u16;
typedef unsigned int u32;
typedef unsigned long long u64;
typedef __attribute__((ext_vector_type(8))) short bf16x8;
typedef __attribute__((ext_vector_type(8))) unsigned short u16x8;
typedef __attribute__((ext_vector_type(4))) unsigned short u16x4;
typedef __attribute__((ext_vector_type(4))) float f32x4;

#define DEVI static __device__ __forceinline__
#define MFMA __builtin_amdgcn_mfma_f32_16x16x32_bf16

constexpr int B = 32, S = 128, T = 64, H = 512, V = 32000;
constexpr int H4 = 4 * H;          // 2048
constexpr int TD = T - 1;          // 63 decoder steps
constexpr int MOUT = TD * B;       // 2016
constexpr int KOUT = 3 * H;        // 1536
constexpr int PAD_IDX = 1;

DEVI u16 f2bf(float f) {
  union { float f; unsigned u; } v; v.f = f;
  unsigned r = (v.u + 0x7fffu + ((v.u >> 16) & 1u)) >> 16;
  return (u16)r;
}
DEVI float bf2f(u16 h) {
  union { unsigned u; float f; } v; v.u = ((unsigned)h) << 16;
  return v.f;
}
DEVI float sigm(float x) { return 1.f / (1.f + __expf(-x)); }
DEVI float tanh_(float x) {
  float ax = fabsf(x);
  float e = __expf(-2.f * ax);
  float t = (1.f - e) / (1.f + e);
  return x < 0.f ? -t : t;
}
DEVI float tanhf_(float x) {
  float e = __expf(2.f * x);
  return 1.f - 2.f * __builtin_amdgcn_rcpf(e + 1.f);
}
DEVI int swz(int row, int k8) { return row * 32 + ((k8 ^ (row & 3)) << 3); }

DEVI u64 pack4u(const u16* p) {
  return (u64)p[0] | ((u64)p[1] << 16) | ((u64)p[2] << 32) | ((u64)p[3] << 48);
}
// data write-through to coherence point; returned old keeps vmcnt honest
DEVI u64 xstore(u16* p, u64 v) {
  return __hip_atomic_exchange((u64*)p, v, __ATOMIC_RELAXED,
                               __HIP_MEMORY_SCOPE_AGENT);
}
DEVI void sstore(unsigned* p, unsigned v) {
  __hip_atomic_exchange(p, v, __ATOMIC_RELAXED, __HIP_MEMORY_SCOPE_AGENT);
}
// poll with light backoff; loads only, 64B-strided slots
DEVI void poll_bo(unsigned* p, unsigned tgt) {
  int it = 0;
  long long t0 = (long long)__builtin_amdgcn_s_memrealtime();
  while (__hip_atomic_load(p, __ATOMIC_RELAXED, __HIP_MEMORY_SCOPE_AGENT) <
         tgt) {
    if (it < 4) {
      __builtin_amdgcn_s_sleep(1);
      it++;
    } else {
      __builtin_amdgcn_s_sleep(8);
    }
    if ((long long)__builtin_amdgcn_s_memrealtime() - t0 > 20000000ll) break;
  }
}

// ---------------- bf16 MFMA GEMM:  C[M,N] = A[M,K] * Bt[N,K]^T + bias ------
__global__ __launch_bounds__(256) void gemm_bt(
    const u16* __restrict__ A, int lda,
    const u16* __restrict__ Bt, int ldb,
    float* __restrict__ C, int ldc,
    const float* __restrict__ bias, int M, int K, int bf16out) {
  __shared__ u16 As[128 * 32], Bs[128 * 32];
  const int tid = threadIdx.x;
  const int m0 = blockIdx.y * 128, n0 = blockIdx.x * 128;
  const int lane = tid & 63, w = tid >> 6, wm = w >> 1, wn = w & 1;
  const int lr = lane & 15, lk = lane >> 4;
  f32x4 acc[4][4] = {};
  const int r = tid >> 1, cc = (tid & 1) * 16, k8b = (tid & 1) * 2;

  for (int k0 = 0; k0 < K; k0 += 32) {
    {
      long gr = m0 + r;
      u16x8 v0 = {}, v1 = {};
      if (gr < M) {
        const u16* s = A + gr * (long)lda + k0 + cc;
        v0 = *(const u16x8*)s;
        v1 = *(const u16x8*)(s + 8);
      }
      *(u16x8*)&As[swz(r, k8b)] = v0;
      *(u16x8*)&As[swz(r, k8b + 1)] = v1;
    }
    {
      const u16* s = Bt + (long)(n0 + r) * ldb + k0 + cc;
      u16x8 v0 = *(const u16x8*)s;
      u16x8 v1 = *(const u16x8*)(s + 8);
      *(u16x8*)&Bs[swz(r, k8b)] = v0;
      *(u16x8*)&Bs[swz(r, k8b + 1)] = v1;
    }
    __syncthreads();
    bf16x8 af[4], bfr[4];
#pragma unroll
    for (int mi = 0; mi < 4; mi++)
      af[mi] = *(const bf16x8*)&As[swz(wm * 64 + mi * 16 + lr, lk)];
#pragma unroll
    for (int ni = 0; ni < 4; ni++)
      bfr[ni] = *(const bf16x8*)&Bs[swz(wn * 64 + ni * 16 + lr, lk)];
#pragma unroll
    for (int mi = 0; mi < 4; mi++)
#pragma unroll
      for (int ni = 0; ni < 4; ni++)
        acc[mi][ni] = MFMA(af[mi], bfr[ni], acc[mi][ni], 0, 0, 0);
    __syncthreads();
  }
#pragma unroll
  for (int ni = 0; ni < 4; ni++) {
    int col = n0 + wn * 64 + ni * 16 + lr;
    float bs = bias ? bias[col] : 0.f;
#pragma unroll
    for (int mi = 0; mi < 4; mi++) {
#pragma unroll
      for (int rr = 0; rr < 4; rr++) {
        long row = m0 + wm * 64 + mi * 16 + lk * 4 + rr;
        if (row < M) {
          float v = acc[mi][ni][rr] + bs;
          if (bf16out)
            ((u16*)C)[row * (long)ldc + col] = f2bf(v);
          else
            C[row * (long)ldc + col] = v;
        }
      }
    }
  }
}

// ---------------- helpers ---------------------------------------------------
__global__ void zero_f(float* p, long n) {
  long i = (long)blockIdx.x * 256 + threadIdx.x;
  long st = (long)gridDim.x * 256;
  for (; i < n; i += st) p[i] = 0.f;
}

__global__ void zero_u(unsigned* p, int n) {
  int i = blockIdx.x * 256 + threadIdx.x;
  if (i < n) p[i] = 0u;
}

__global__ void cast_bf(const float* __restrict__ src, u16* __restrict__ dst,
                        int ld, int off, int Csz) {
  long row = blockIdx.y;
  int col = blockIdx.x * 256 + threadIdx.x;
  dst[row * Csz + col] = f2bf(src[row * ld + off + col]);
}

__global__ void cast_bf4(const float* __restrict__ src, u16* __restrict__ dst,
                         long n4) {
  long i = (long)blockIdx.x * 256 + threadIdx.x;
  if (i >= n4) return;
  float4 v = ((const float4*)src)[i];
  u16x4 o;
  o[0] = f2bf(v.x); o[1] = f2bf(v.y); o[2] = f2bf(v.z); o[3] = f2bf(v.w);
  *(u16x4*)&dst[i * 4] = o;
}

// permuted-row cast: dst row n' = src row (g*H + jH), n' = jH*4 + g
__global__ void cast_perm(const float* __restrict__ src, int ld, int off,
                          u16* __restrict__ dst) {
  int np = blockIdx.y;
  int c = blockIdx.x * 256 + threadIdx.x;
  int g = np & 3, jH = np >> 2;
  dst[(size_t)np * H + c] = f2bf(src[(size_t)(g * H + jH) * ld + off + c]);
}

// wdec_p row r = j*4+g, cols [0:512)=wih weighted-part, [512:1024)=whh
__global__ void pack_wdec_p(const float* __restrict__ wih,
                            const float* __restrict__ whh,
                            u16* __restrict__ dst) {
  int r = blockIdx.y;                      // 0..2047
  int k = blockIdx.x * 256 + threadIdx.x;  // 0..1023
  int g = r & 3, j = r >> 2;
  int srow = g * H + j;
  float v = (k < 512) ? wih[(size_t)srow * (2 * H) + 512 + k]
                      : whh[(size_t)srow * H + (k - 512)];
  dst[(size_t)r * 1024 + k] = f2bf(v);
}

__global__ void bias_perm(const float* __restrict__ a,
                          const float* __restrict__ b, float* __restrict__ o) {
  int np = blockIdx.x * 256 + threadIdx.x;
  int g = np & 3, jH = np >> 2;
  int r = g * H + jH;
  o[np] = a[r] + b[r];
}

// dst[c*R + r] = bf16(src[r*ld + off + c]); grid (C/32, R/32)
__global__ __launch_bounds__(256) void cast_transpose_bf(
    const float* __restrict__ src, int ld, int off, u16* __restrict__ dst,
    int R) {
  __shared__ float tile[32][33];
  int r0 = blockIdx.y * 32, c0 = blockIdx.x * 32;
  int tx = threadIdx.x & 31, ty = threadIdx.x >> 5;
#pragma unroll
  for (int i = 0; i < 32; i += 8)
    tile[ty + i][tx] = src[(long)(r0 + ty + i) * ld + off + c0 + tx];
  __syncthreads();
#pragma unroll
  for (int i = 0; i < 32; i += 8)
    dst[(long)(c0 + ty + i) * R + r0 + tx] = f2bf(tile[tx][ty + i]);
}

__global__ void gather_src_emb(const int* __restrict__ src,
                               const float* __restrict__ emb,
                               u16* __restrict__ dst) {
  int row = blockIdx.y;           // row = t*B + b
  int t = row >> 5, b = row & 31;
  int c = blockIdx.x * 256 + threadIdx.x;
  int tok = src[b * S + t];
  dst[(long)row * H + c] = f2bf(emb[(long)tok * H + c]);
}

__global__ void gather_trg_emb(const int* __restrict__ trg,
                               const float* __restrict__ emb,
                               u16* __restrict__ xout) {
  int row = blockIdx.y;           // row = t*B + b, t < 63
  int t = row >> 5, b = row & 31;
  int c = blockIdx.x * 256 + threadIdx.x;
  int tok = trg[b * T + t];
  xout[(long)row * KOUT + 2 * H + c] = f2bf(emb[(long)tok * H + c]);
}

// ---------------- persistent encoder: 32 blocks x 512 ----------------------
// Block bk owns j-cols [bk*16, bk*16+16) (=64 permuted gate rows) for all B.
// Weights streamed from L2 (per-block 64 KB slice). hstep[0] pre-zeroed.
__global__ __launch_bounds__(512) void enc_persist32(
    unsigned* fes, const u16* __restrict__ wenc_p,
    const float* __restrict__ xih_p, u16* hstep, u16* enc_bt_bf, float* cbuf) {
  __shared__ float gs[32][64];
  __shared__ float c_s[512];
  __shared__ u16 hx[512];
  const int tid = threadIdx.x, bk = blockIdx.x;
  const int wave = tid >> 6, lane = tid & 63;
  const int lr = lane & 15, lk = lane >> 4;
  const int bq = tid >> 4, jl = tid & 15;
  c_s[tid] = 0.f;
  const int mt = wave & 1, nt = wave >> 1;
  const int n = nt * 16 + lr;
  const u16* wp = wenc_p + (size_t)(bk * 64 + n) * 512 + lk * 8;
  for (int t = 0; t < S; t++) {
    if (t > 0 && tid < 32) poll_bo(fes + tid * 16, (unsigned)t);
    __syncthreads();
    float4 xv = *(const float4*)(xih_p + ((size_t)t * B + bq) * H4 +
                                 (bk * 16 + jl) * 4);
    {
      const u16* ab =
          hstep + (size_t)t * B * H + (size_t)(mt * 16 + lr) * H + lk * 8;
      f32x4 acc = {};
#pragma unroll
      for (int kt = 0; kt < 16; kt++) {
        bf16x8 a = *(const bf16x8*)(ab + kt * 32);
        bf16x8 w = *(const bf16x8*)(wp + kt * 32);
        acc = MFMA(a, w, acc, 0, 0, 0);
      }
#pragma unroll
      for (int rr = 0; rr < 4; rr++) gs[mt * 16 + lk * 4 + rr][n] = acc[rr];
    }
    __syncthreads();
    {
      float gi = xv.x + gs[bq][jl * 4 + 0];
      float gf = xv.y + gs[bq][jl * 4 + 1];
      float gg = xv.z + gs[bq][jl * 4 + 2];
      float go = xv.w + gs[bq][jl * 4 + 3];
      float cn = sigm(gf) * c_s[tid] + sigm(gi) * tanh_(gg);
      c_s[tid] = cn;
      u16 h16 = f2bf(sigm(go) * tanh_(cn));
      hx[tid] = h16;
      enc_bt_bf[((size_t)bq * S + t) * H + bk * 16 + jl] = h16;
    }
    __syncthreads();
    u64 kp = 0;
    if (tid < 128) {
      int bb = tid >> 2, q = tid & 3;
      kp = xstore(hstep + (size_t)(t + 1) * B * H + (size_t)bb * H + bk * 16 +
                      q * 4,
                  pack4u(&hx[bb * 16 + q * 4]));
    }
    if (wave < 2) {
      asm volatile("" :: "v"(kp));
      asm volatile("s_waitcnt vmcnt(0)" ::: "memory");
    }
    __syncthreads();
    if (tid == 0) sstore(fes + bk * 16, (unsigned)(t + 1));
  }
  cbuf[bq * H + bk * 16 + jl] = c_s[tid];
}

// ---------------- persistent decoder: 32 blocks x 512 ----------------------
// Block bk: full attention for batch bk + LSTM for j-cols [bk*16,+16) all B.
__global__ __launch_bounds__(512) void dec_persist32(
    unsigned* fhs, unsigned* fws, const float* __restrict__ fc_w,
    const float* __restrict__ fc_b, const u16* __restrict__ wdec_p,
    const u16* __restrict__ a1T_bf, const float* __restrict__ attn_v,
    const int* __restrict__ src, const u16* __restrict__ hf_bf,
    const float* __restrict__ cbuf, const u16* __restrict__ epart_bf,
    const u16* __restrict__ enc_bt_bf, const float* __restrict__ eih_p,
    u16* hstep, u16* wstep, u16* __restrict__ xout_bf) {
  __shared__ float buf[8][512];   // attn partials / gate results (union)
  __shared__ float hs[512], hps[512];
  __shared__ float sc[128], red[2];
  __shared__ int smask[128];
  __shared__ float c_s[512];
  __shared__ u16 hx[512];
  const int tid = threadIdx.x, bk = blockIdx.x;
  const int wave = tid >> 6, lane = tid & 63;
  const int lr = lane & 15, lk = lane >> 4;
  const int bq = tid >> 4, jl = tid & 15;
  c_s[tid] = cbuf[bq * H + bk * 16 + jl];
  if (tid < 128) smask[tid] = src[bk * S + tid];
  float av8[8];
#pragma unroll
  for (int e = 0; e < 8; e++) av8[e] = attn_v[lane * 8 + e];
  // fc: hidden = tanh(hf @ fc_w^T + fc_b) -> h[0] slice (waves 0,1)
  if (wave < 2) {
    const u16* ab = hf_bf + (size_t)(wave * 16 + lr) * H + lk * 8;
    const float* frow = fc_w + (size_t)(bk * 16 + lr) * H + lk * 8;
    f32x4 acc = {};
#pragma unroll
    for (int kt = 0; kt < 16; kt++) {
      bf16x8 a = *(const bf16x8*)(ab + kt * 32);
      bf16x8 w;
#pragma unroll
      for (int e = 0; e < 8; e++) w[e] = (short)f2bf(frow[kt * 32 + e]);
      acc = MFMA(a, w, acc, 0, 0, 0);
    }
    float bs = fc_b[bk * 16 + lr];
#pragma unroll
    for (int rr = 0; rr < 4; rr++)
      hx[(wave * 16 + lk * 4 + rr) * 16 + lr] = f2bf(tanh_(acc[rr] + bs));
  }
  __syncthreads();
  {
    u64 kp = 0;
    if (tid < 128) {
      int bb = tid >> 2, q = tid & 3;
      kp = xstore(hstep + (size_t)bb * H + bk * 16 + q * 4,
                  pack4u(&hx[bb * 16 + q * 4]));
    }
    if (wave < 2) {
      asm volatile("" :: "v"(kp));
      asm volatile("s_waitcnt vmcnt(0)" ::: "memory");
    }
    __syncthreads();
    if (tid == 0) sstore(fhs + bk * 16, 1u);
  }
  // gate weight slice pointers (L2-hot streams)
  const int mt = wave & 1, nt = wave >> 1;
  const int n = nt * 16 + lr;
  const u16* wpw = wdec_p + (size_t)(bk * 64 + n) * 1024 + lk * 8;
  const u16* wph = wpw + 512;
  // ---- time loop ----
  for (int t = 0; t < TD; t++) {
    if (tid < 32) poll_bo(fhs + tid * 16, (unsigned)(t + 1));
    __syncthreads();
    float4 xv = *(const float4*)(eih_p + ((size_t)t * B + bq) * H4 +
                                 (bk * 16 + jl) * 4);
    // --- attention for own batch bk ---
    if (tid < 256) {
      u32 v = ((const u32*)(hstep + (size_t)t * B * H + (size_t)bk * H))[tid];
      hs[2 * tid] = bf2f((u16)(v & 0xffff));
      hs[2 * tid + 1] = bf2f((u16)(v >> 16));
    }
    __syncthreads();
    {  // hp partials: wave w covers k in [w*64, w*64+64)
      float p[8] = {};
      const int j0 = lane * 8;
#pragma unroll 4
      for (int kk = 0; kk < 64; kk++) {
        int k = wave * 64 + kk;
        float hk = hs[k];
        u16x8 av = *(const u16x8*)&a1T_bf[(size_t)k * H + j0];
#pragma unroll
        for (int e = 0; e < 8; e++) p[e] += hk * bf2f(av[e]);
      }
#pragma unroll
      for (int e = 0; e < 8; e++) buf[wave][j0 + e] = p[e];
    }
    __syncthreads();
    {
      float s0 = 0.f;
#pragma unroll
      for (int w = 0; w < 8; w++) s0 += buf[w][tid];
      hps[tid] = s0;
    }
    __syncthreads();
    {  // scores: wave w covers s in [w*16, w*16+16)
      const int j0 = lane * 8;
      float hp8[8];
#pragma unroll
      for (int e = 0; e < 8; e++) hp8[e] = hps[j0 + e];
      for (int i = 0; i < 16; i++) {
        int s = wave * 16 + i;
        u16x8 ep = *(const u16x8*)&epart_bf[((size_t)bk * S + s) * H + j0];
        float a = 0.f;
#pragma unroll
        for (int e = 0; e < 8; e++) a += av8[e] * tanhf_(hp8[e] + bf2f(ep[e]));
#pragma unroll
        for (int o = 32; o; o >>= 1) a += __shfl_xor(a, o);
        if (lane == 0) sc[s] = (smask[s] == PAD_IDX) ? -1e10f : a;
      }
    }
    __syncthreads();
    if (tid < 64) {
      float v = fmaxf(sc[tid], sc[tid + 64]);
#pragma unroll
      for (int o = 32; o; o >>= 1) v = fmaxf(v, __shfl_xor(v, o));
      if (tid == 0) red[0] = v;
    }
    __syncthreads();
    float mx = red[0];
    if (tid < S) sc[tid] = __expf(sc[tid] - mx);
    __syncthreads();
    if (tid < 64) {
      float v = sc[tid] + sc[tid + 64];
#pragma unroll
      for (int o = 32; o; o >>= 1) v += __shfl_xor(v, o);
      if (tid == 0) red[1] = 1.f / v;
    }
    __syncthreads();
    {  // weighted partials: wave w owns s in [w*16, w*16+16)
      float acc8[8] = {};
      const int j0 = lane * 8;
      for (int i = 0; i < 16; i++) {
        int s = wave * 16 + i;
        float ps = sc[s];
        u16x8 ev = *(const u16x8*)&enc_bt_bf[((size_t)bk * S + s) * H + j0];
#pragma unroll
        for (int e = 0; e < 8; e++) acc8[e] += ps * bf2f(ev[e]);
      }
#pragma unroll
      for (int e = 0; e < 8; e++) buf[wave][j0 + e] = acc8[e];
    }
    __syncthreads();
    {  // finalize + publish w (own batch)
      u64 kp = 0;
      if (tid < 128) {
        float inv = red[1];
        int j0 = tid * 4;
        u16x4 o;
#pragma unroll
        for (int i = 0; i < 4; i++) {
          float wj = (buf[0][j0 + i] + buf[1][j0 + i] + buf[2][j0 + i] +
                      buf[3][j0 + i] + buf[4][j0 + i] + buf[5][j0 + i] +
                      buf[6][j0 + i] + buf[7][j0 + i]) *
                     inv;
          o[i] = f2bf(wj);
        }
        *(u16x4*)&xout_bf[((size_t)t * B + bk) * KOUT + H + j0] = o;
        u64 val = (u64)o[0] | ((u64)o[1] << 16) | ((u64)o[2] << 32) |
                  ((u64)o[3] << 48);
        kp = xstore(wstep + ((size_t)t * B + bk) * H + j0, val);
      }
      if (wave < 2) {
        asm volatile("" :: "v"(kp));
        asm volatile("s_waitcnt vmcnt(0)" ::: "memory");
      }
      __syncthreads();
      if (tid == 0) sstore(fws + bk * 16, (unsigned)(t + 1));
    }
    // --- gates: M=32, N=64, K=1024 ([w|h]) ---
    if (tid < 32) poll_bo(fws + tid * 16, (unsigned)(t + 1));
    __syncthreads();
    {
      const u16* aw =
          wstep + (size_t)t * B * H + (size_t)(mt * 16 + lr) * H + lk * 8;
      const u16* ah =
          hstep + (size_t)t * B * H + (size_t)(mt * 16 + lr) * H + lk * 8;
      f32x4 acc = {};
#pragma unroll
      for (int kt = 0; kt < 16; kt++) {
        bf16x8 a = *(const bf16x8*)(aw + kt * 32);
        bf16x8 w = *(const bf16x8*)(wpw + kt * 32);
        acc = MFMA(a, w, acc, 0, 0, 0);
      }
#pragma unroll
      for (int kt = 0; kt < 16; kt++) {
        bf16x8 a = *(const bf16x8*)(ah + kt * 32);
        bf16x8 w = *(const bf16x8*)(wph + kt * 32);
        acc = MFMA(a, w, acc, 0, 0, 0);
      }
      float* gsp = &buf[0][0];
#pragma unroll
      for (int rr = 0; rr < 4; rr++)
        gsp[(mt * 16 + lk * 4 + rr) * 64 + n] = acc[rr];
    }
    __syncthreads();
    {  // pointwise
      const float* gsp = &buf[0][0];
      float gi = xv.x + gsp[bq * 64 + jl * 4 + 0];
      float gf = xv.y + gsp[bq * 64 + jl * 4 + 1];
      float gg = xv.z + gsp[bq * 64 + jl * 4 + 2];
      float go = xv.w + gsp[bq * 64 + jl * 4 + 3];
      float cn = sigm(gf) * c_s[tid] + sigm(gi) * tanh_(gg);
      c_s[tid] = cn;
      u16 h16 = f2bf(sigm(go) * tanh_(cn));
      hx[tid] = h16;
      xout_bf[((size_t)t * B + bq) * KOUT + bk * 16 + jl] = h16;
    }
    __syncthreads();
    {  // publish h slice
      u64 kp = 0;
      if (tid < 128) {
        int bb = tid >> 2, q = tid & 3;
        kp = xstore(hstep + (size_t)(t + 1) * B * H + (size_t)bb * H +
                        bk * 16 + q * 4,
                    pack4u(&hx[bb * 16 + q * 4]));
      }
      if (wave < 2) {
        asm volatile("" :: "v"(kp));
        asm volatile("s_waitcnt vmcnt(0)" ::: "memory");
      }
      __syncthreads();
      if (tid == 0) sstore(fhs + bk * 16, (unsigned)(t + 2));
    }
  }
}

// ---------------------------------------------------------------------------
extern "C" void kernel_launch(void* const* d_in, const int* in_sizes, int n_in,
                              void* d_out, int out_size, void* d_ws,
                              size_t ws_size, hipStream_t stream) {
  const int* src = (const int*)d_in[0];
  const int* trg = (const int*)d_in[2];
  const float* enc_emb = (const float*)d_in[3];
  const float* enc_wih = (const float*)d_in[4];
  const float* enc_whh = (const float*)d_in[5];
  const float* enc_bih = (const float*)d_in[6];
  const float* enc_bhh = (const float*)d_in[7];
  const float* fc_w = (const float*)d_in[8];
  const float* fc_b = (const float*)d_in[9];
  const float* dec_emb = (const float*)d_in[10];
  const float* attn_w = (const float*)d_in[11];
  const float* attn_b = (const float*)d_in[12];
  const float* attn_v = (const float*)d_in[13];
  const float* dec_wih = (const float*)d_in[14];
  const float* dec_whh = (const float*)d_in[15];
  const float* dec_bih = (const float*)d_in[16];
  const float* dec_bhh = (const float*)d_in[17];
  const float* out_w = (const float*)d_in[18];
  const float* out_b = (const float*)d_in[19];
  float* out = (float*)d_out;

  char* wp = (char*)d_ws;
  auto alloc = [&](size_t n) {
    char* p = wp;
    wp += (n + 255) & ~(size_t)255;
    return p;
  };
  u16* outw_bf = (u16*)alloc((size_t)V * KOUT * 2);        // 98.3 MB
  u16* wihenc_p = (u16*)alloc((size_t)H4 * H * 2);         // 2.1 MB
  u16* wihE_p = (u16*)alloc((size_t)H4 * H * 2);           // 2.1 MB
  u16* wenc_p = (u16*)alloc((size_t)H4 * H * 2);           // 2.1 MB
  u16* wdec_p = (u16*)alloc((size_t)H4 * 2 * H * 2);       // 8.4 MB
  u16* attnw2_bf = (u16*)alloc((size_t)H * H * 2);         // 0.5 MB
  u16* a1T_bf = (u16*)alloc((size_t)H * H * 2);            // 0.5 MB
  u16* xemb_bf = (u16*)alloc((size_t)S * B * H * 2);       // 4.2 MB
  float* xih_p = (float*)alloc((size_t)S * B * H4 * 4);    // 33.6 MB
  u16* enc_bt_bf = (u16*)alloc((size_t)B * S * H * 2);     // 4.2 MB
  u16* epart_bf = (u16*)alloc((size_t)B * S * H * 2);      // 4.2 MB
  float* eih_p = (float*)alloc((size_t)MOUT * H4 * 4);     // 16.5 MB
  u16* xout_bf = (u16*)alloc((size_t)MOUT * KOUT * 2);     // 6.2 MB
  u16* hstep_enc = (u16*)alloc((size_t)(S + 1) * B * H * 2);  // 4.3 MB
  u16* hstep_dec = (u16*)alloc((size_t)T * B * H * 2);        // 2.1 MB
  u16* wstep = (u16*)alloc((size_t)TD * B * H * 2);           // 2.1 MB
  float* cbuf = (float*)alloc((size_t)B * H * 4);
  float* benc_p = (float*)alloc((size_t)H4 * 4);
  float* bdec_p = (float*)alloc((size_t)H4 * 4);
  unsigned* flags = (unsigned*)alloc(2048 * 4);
  unsigned* fes = flags;            // 32 slots x 16 u32
  unsigned* fhs = flags + 512;      // 32 slots x 16 u32
  unsigned* fws = flags + 1024;     // 32 slots x 16 u32

  dim3 blk(256);
  zero_f<<<dim3(256), blk, 0, stream>>>(out, (long)B * V);
  zero_u<<<dim3(8), blk, 0, stream>>>(flags, 2048);
  zero_u<<<dim3(32), blk, 0, stream>>>((unsigned*)hstep_enc, B * H / 2);
  // weight preparation
  cast_bf4<<<dim3(((long)V * KOUT / 4 + 255) / 256), blk, 0, stream>>>(
      out_w, outw_bf, (long)V * KOUT / 4);
  cast_perm<<<dim3(H / 256, H4), blk, 0, stream>>>(enc_wih, H, 0, wihenc_p);
  cast_perm<<<dim3(H / 256, H4), blk, 0, stream>>>(dec_wih, 2 * H, 0, wihE_p);
  cast_perm<<<dim3(H / 256, H4), blk, 0, stream>>>(enc_whh, H, 0, wenc_p);
  pack_wdec_p<<<dim3(4, H4), blk, 0, stream>>>(dec_wih, dec_whh, wdec_p);
  cast_bf<<<dim3(H / 256, H), blk, 0, stream>>>(attn_w, attnw2_bf, 2 * H, H, H);
  cast_transpose_bf<<<dim3(H / 32, H / 32), blk, 0, stream>>>(attn_w, 2 * H, 0,
                                                              a1T_bf, H);
  bias_perm<<<dim3(H4 / 256), blk, 0, stream>>>(enc_bih, enc_bhh, benc_p);
  bias_perm<<<dim3(H4 / 256), blk, 0, stream>>>(dec_bih, dec_bhh, bdec_p);
  gather_src_emb<<<dim3(H / 256, S * B), blk, 0, stream>>>(src, enc_emb,
                                                           xemb_bf);
  gather_trg_emb<<<dim3(H / 256, MOUT), blk, 0, stream>>>(trg, dec_emb,
                                                          xout_bf);
  // input-side GEMMs (permuted cols, biases folded)
  gemm_bt<<<dim3(H4 / 128, (S * B) / 128), blk, 0, stream>>>(
      xemb_bf, H, wihenc_p, H, xih_p, H4, benc_p, S * B, H, 0);
  gemm_bt<<<dim3(H4 / 128, (MOUT + 127) / 128), blk, 0, stream>>>(
      xout_bf + 2 * H, KOUT, wihE_p, H, eih_p, H4, bdec_p, MOUT, H, 0);
  // persistent encoder
  enc_persist32<<<dim3(32), dim3(512), 0, stream>>>(fes, wenc_p, xih_p,
                                                    hstep_enc, enc_bt_bf, cbuf);
  // epart = enc_bt @ attn_w2^T + attn_b  (bf16 out)
  gemm_bt<<<dim3(H / 128, (B * S) / 128), blk, 0, stream>>>(
      enc_bt_bf, H, attnw2_bf, H, (float*)epart_bf, H, attn_b, B * S, H, 1);
  // persistent decoder (h_f = hstep_enc step S)
  dec_persist32<<<dim3(32), dim3(512), 0, stream>>>(
      fhs, fws, fc_w, fc_b, wdec_p, a1T_bf, attn_v, src,
      hstep_enc + (size_t)S * B * H, cbuf, epart_bf, enc_bt_bf, eih_p,
      hstep_dec, wstep, xout_bf);
  // final logits GEMM
  gemm_bt<<<dim3(V / 128, (MOUT + 127) / 128), blk, 0, stream>>>(
      xout_bf, KOUT, outw_bf, KOUT, out + (size_t)B * V, V, out_b, MOUT, KOUT,
      0);
}

// Round 10
// 3181.820 us; speedup vs baseline: 6.6422x; 1.0262x over previous
//
#include <hip/hip_runtime.h>

typedef unsigned short u16;
typedef unsigned int u32;
typedef unsigned long long u64;
typedef __attribute__((ext_vector_type(8))) short bf16x8;
typedef __attribute__((ext_vector_type(8))) unsigned short u16x8;
typedef __attribute__((ext_vector_type(4))) unsigned short u16x4;
typedef __attribute__((ext_vector_type(4))) float f32x4;

#define DEVI static __device__ __forceinline__
#define MFMA __builtin_amdgcn_mfma_f32_16x16x32_bf16

constexpr int B = 32, S = 128, T = 64, H = 512, V = 32000;
constexpr int H4 = 4 * H;          // 2048
constexpr int TD = T - 1;          // 63 decoder steps
constexpr int MOUT = TD * B;       // 2016
constexpr int KOUT = 3 * H;        // 1536
constexpr int PAD_IDX = 1;

DEVI u16 f2bf(float f) {
  union { float f; unsigned u; } v; v.f = f;
  unsigned r = (v.u + 0x7fffu + ((v.u >> 16) & 1u)) >> 16;
  return (u16)r;
}
DEVI float bf2f(u16 h) {
  union { unsigned u; float f; } v; v.u = ((unsigned)h) << 16;
  return v.f;
}
DEVI float sigm(float x) { return 1.f / (1.f + __expf(-x)); }
DEVI float tanh_(float x) {
  float ax = fabsf(x);
  float e = __expf(-2.f * ax);
  float t = (1.f - e) / (1.f + e);
  return x < 0.f ? -t : t;
}
DEVI float tanhf_(float x) {
  float e = __expf(2.f * x);
  return 1.f - 2.f * __builtin_amdgcn_rcpf(e + 1.f);
}
DEVI int swz(int row, int k8) { return row * 32 + ((k8 ^ (row & 3)) << 3); }

DEVI u64 pack4u(const u16* p) {
  return (u64)p[0] | ((u64)p[1] << 16) | ((u64)p[2] << 32) | ((u64)p[3] << 48);
}
// data write-through to coherence point; returned old keeps vmcnt honest
DEVI u64 xstore(u16* p, u64 v) {
  return __hip_atomic_exchange((u64*)p, v, __ATOMIC_RELAXED,
                               __HIP_MEMORY_SCOPE_AGENT);
}
DEVI void sstore(unsigned* p, unsigned v) {
  __hip_atomic_exchange(p, v, __ATOMIC_RELAXED, __HIP_MEMORY_SCOPE_AGENT);
}
// poll with light backoff; loads only, 64B-strided slots
DEVI void poll_bo(unsigned* p, unsigned tgt) {
  int it = 0;
  long long t0 = (long long)__builtin_amdgcn_s_memrealtime();
  while (__hip_atomic_load(p, __ATOMIC_RELAXED, __HIP_MEMORY_SCOPE_AGENT) <
         tgt) {
    if (it < 4) {
      __builtin_amdgcn_s_sleep(1);
      it++;
    } else {
      __builtin_amdgcn_s_sleep(8);
    }
    if ((long long)__builtin_amdgcn_s_memrealtime() - t0 > 20000000ll) break;
  }
}

// ---------------- bf16 MFMA GEMM:  C[M,N] = A[M,K] * Bt[N,K]^T + bias ------
__global__ __launch_bounds__(256) void gemm_bt(
    const u16* __restrict__ A, int lda,
    const u16* __restrict__ Bt, int ldb,
    float* __restrict__ C, int ldc,
    const float* __restrict__ bias, int M, int K, int bf16out) {
  __shared__ u16 As[128 * 32], Bs[128 * 32];
  const int tid = threadIdx.x;
  const int m0 = blockIdx.y * 128, n0 = blockIdx.x * 128;
  const int lane = tid & 63, w = tid >> 6, wm = w >> 1, wn = w & 1;
  const int lr = lane & 15, lk = lane >> 4;
  f32x4 acc[4][4] = {};
  const int r = tid >> 1, cc = (tid & 1) * 16, k8b = (tid & 1) * 2;

  for (int k0 = 0; k0 < K; k0 += 32) {
    {
      long gr = m0 + r;
      u16x8 v0 = {}, v1 = {};
      if (gr < M) {
        const u16* s = A + gr * (long)lda + k0 + cc;
        v0 = *(const u16x8*)s;
        v1 = *(const u16x8*)(s + 8);
      }
      *(u16x8*)&As[swz(r, k8b)] = v0;
      *(u16x8*)&As[swz(r, k8b + 1)] = v1;
    }
    {
      const u16* s = Bt + (long)(n0 + r) * ldb + k0 + cc;
      u16x8 v0 = *(const u16x8*)s;
      u16x8 v1 = *(const u16x8*)(s + 8);
      *(u16x8*)&Bs[swz(r, k8b)] = v0;
      *(u16x8*)&Bs[swz(r, k8b + 1)] = v1;
    }
    __syncthreads();
    bf16x8 af[4], bfr[4];
#pragma unroll
    for (int mi = 0; mi < 4; mi++)
      af[mi] = *(const bf16x8*)&As[swz(wm * 64 + mi * 16 + lr, lk)];
#pragma unroll
    for (int ni = 0; ni < 4; ni++)
      bfr[ni] = *(const bf16x8*)&Bs[swz(wn * 64 + ni * 16 + lr, lk)];
#pragma unroll
    for (int mi = 0; mi < 4; mi++)
#pragma unroll
      for (int ni = 0; ni < 4; ni++)
        acc[mi][ni] = MFMA(af[mi], bfr[ni], acc[mi][ni], 0, 0, 0);
    __syncthreads();
  }
#pragma unroll
  for (int ni = 0; ni < 4; ni++) {
    int col = n0 + wn * 64 + ni * 16 + lr;
    float bs = bias ? bias[col] : 0.f;
#pragma unroll
    for (int mi = 0; mi < 4; mi++) {
#pragma unroll
      for (int rr = 0; rr < 4; rr++) {
        long row = m0 + wm * 64 + mi * 16 + lk * 4 + rr;
        if (row < M) {
          float v = acc[mi][ni][rr] + bs;
          if (bf16out)
            ((u16*)C)[row * (long)ldc + col] = f2bf(v);
          else
            C[row * (long)ldc + col] = v;
        }
      }
    }
  }
}

// ---------------- helpers ---------------------------------------------------
__global__ void zero_f(float* p, long n) {
  long i = (long)blockIdx.x * 256 + threadIdx.x;
  long st = (long)gridDim.x * 256;
  for (; i < n; i += st) p[i] = 0.f;
}

__global__ void zero_u(unsigned* p, int n) {
  int i = blockIdx.x * 256 + threadIdx.x;
  if (i < n) p[i] = 0u;
}

__global__ void cast_bf(const float* __restrict__ src, u16* __restrict__ dst,
                        int ld, int off, int Csz) {
  long row = blockIdx.y;
  int col = blockIdx.x * 256 + threadIdx.x;
  dst[row * Csz + col] = f2bf(src[row * ld + off + col]);
}

__global__ void cast_bf4(const float* __restrict__ src, u16* __restrict__ dst,
                         long n4) {
  long i = (long)blockIdx.x * 256 + threadIdx.x;
  if (i >= n4) return;
  float4 v = ((const float4*)src)[i];
  u16x4 o;
  o[0] = f2bf(v.x); o[1] = f2bf(v.y); o[2] = f2bf(v.z); o[3] = f2bf(v.w);
  *(u16x4*)&dst[i * 4] = o;
}

// permuted-row cast: dst row n' = src row (g*H + jH), n' = jH*4 + g
__global__ void cast_perm(const float* __restrict__ src, int ld, int off,
                          u16* __restrict__ dst) {
  int np = blockIdx.y;
  int c = blockIdx.x * 256 + threadIdx.x;
  int g = np & 3, jH = np >> 2;
  dst[(size_t)np * H + c] = f2bf(src[(size_t)(g * H + jH) * ld + off + c]);
}

// wdec_p row r = j*4+g, cols [0:512)=wih weighted-part, [512:1024)=whh
__global__ void pack_wdec_p(const float* __restrict__ wih,
                            const float* __restrict__ whh,
                            u16* __restrict__ dst) {
  int r = blockIdx.y;                      // 0..2047
  int k = blockIdx.x * 256 + threadIdx.x;  // 0..1023
  int g = r & 3, j = r >> 2;
  int srow = g * H + j;
  float v = (k < 512) ? wih[(size_t)srow * (2 * H) + 512 + k]
                      : whh[(size_t)srow * H + (k - 512)];
  dst[(size_t)r * 1024 + k] = f2bf(v);
}

__global__ void bias_perm(const float* __restrict__ a,
                          const float* __restrict__ b, float* __restrict__ o) {
  int np = blockIdx.x * 256 + threadIdx.x;
  int g = np & 3, jH = np >> 2;
  int r = g * H + jH;
  o[np] = a[r] + b[r];
}

// dst[c*R + r] = bf16(src[r*ld + off + c]); grid (C/32, R/32)
__global__ __launch_bounds__(256) void cast_transpose_bf(
    const float* __restrict__ src, int ld, int off, u16* __restrict__ dst,
    int R) {
  __shared__ float tile[32][33];
  int r0 = blockIdx.y * 32, c0 = blockIdx.x * 32;
  int tx = threadIdx.x & 31, ty = threadIdx.x >> 5;
#pragma unroll
  for (int i = 0; i < 32; i += 8)
    tile[ty + i][tx] = src[(long)(r0 + ty + i) * ld + off + c0 + tx];
  __syncthreads();
#pragma unroll
  for (int i = 0; i < 32; i += 8)
    dst[(long)(c0 + ty + i) * R + r0 + tx] = f2bf(tile[tx][ty + i]);
}

__global__ void gather_src_emb(const int* __restrict__ src,
                               const float* __restrict__ emb,
                               u16* __restrict__ dst) {
  int row = blockIdx.y;           // row = t*B + b
  int t = row >> 5, b = row & 31;
  int c = blockIdx.x * 256 + threadIdx.x;
  int tok = src[b * S + t];
  dst[(long)row * H + c] = f2bf(emb[(long)tok * H + c]);
}

__global__ void gather_trg_emb(const int* __restrict__ trg,
                               const float* __restrict__ emb,
                               u16* __restrict__ xout) {
  int row = blockIdx.y;           // row = t*B + b, t < 63
  int t = row >> 5, b = row & 31;
  int c = blockIdx.x * 256 + threadIdx.x;
  int tok = trg[b * T + t];
  xout[(long)row * KOUT + 2 * H + c] = f2bf(emb[(long)tok * H + c]);
}

// ---------------- persistent encoder: 32 blocks x 512 ----------------------
// Block bk owns j-cols [bk*16, bk*16+16) (=64 permuted gate rows) for all B.
// Weight B-frags register-cached (64 VGPR). hstep[0] pre-zeroed.
__global__ __launch_bounds__(512) void enc_persist32(
    unsigned* fes, const u16* __restrict__ wenc_p,
    const float* __restrict__ xih_p, u16* hstep, u16* enc_bt_bf, float* cbuf) {
  __shared__ float gs[32][64];
  __shared__ float c_s[512];
  __shared__ u16 hx[512];
  const int tid = threadIdx.x, bk = blockIdx.x;
  const int wave = tid >> 6, lane = tid & 63;
  const int lr = lane & 15, lk = lane >> 4;
  const int bq = tid >> 4, jl = tid & 15;
  c_s[tid] = 0.f;
  const int mt = wave & 1, nt = wave >> 1;
  const int n = nt * 16 + lr;
  // register-cache the step-invariant weight fragments
  bf16x8 wf[16];
  {
    const u16* wp = wenc_p + (size_t)(bk * 64 + n) * 512 + lk * 8;
#pragma unroll
    for (int kt = 0; kt < 16; kt++) wf[kt] = *(const bf16x8*)(wp + kt * 32);
  }
  for (int t = 0; t < S; t++) {
    if (t > 0 && tid < 32) poll_bo(fes + tid * 16, (unsigned)t);
    __syncthreads();
    float4 xv = *(const float4*)(xih_p + ((size_t)t * B + bq) * H4 +
                                 (bk * 16 + jl) * 4);
    {
      const u16* ab =
          hstep + (size_t)t * B * H + (size_t)(mt * 16 + lr) * H + lk * 8;
      f32x4 acc = {};
#pragma unroll
      for (int kt = 0; kt < 16; kt++) {
        bf16x8 a = *(const bf16x8*)(ab + kt * 32);
        acc = MFMA(a, wf[kt], acc, 0, 0, 0);
      }
#pragma unroll
      for (int rr = 0; rr < 4; rr++) gs[mt * 16 + lk * 4 + rr][n] = acc[rr];
    }
    __syncthreads();
    {
      float gi = xv.x + gs[bq][jl * 4 + 0];
      float gf = xv.y + gs[bq][jl * 4 + 1];
      float gg = xv.z + gs[bq][jl * 4 + 2];
      float go = xv.w + gs[bq][jl * 4 + 3];
      float cn = sigm(gf) * c_s[tid] + sigm(gi) * tanh_(gg);
      c_s[tid] = cn;
      u16 h16 = f2bf(sigm(go) * tanh_(cn));
      hx[tid] = h16;
      enc_bt_bf[((size_t)bq * S + t) * H + bk * 16 + jl] = h16;
    }
    __syncthreads();
    u64 kp = 0;
    if (tid < 128) {
      int bb = tid >> 2, q = tid & 3;
      kp = xstore(hstep + (size_t)(t + 1) * B * H + (size_t)bb * H + bk * 16 +
                      q * 4,
                  pack4u(&hx[bb * 16 + q * 4]));
    }
    if (wave < 2) {
      asm volatile("" :: "v"(kp));
      asm volatile("s_waitcnt vmcnt(0)" ::: "memory");
    }
    __syncthreads();
    if (tid == 0) sstore(fes + bk * 16, (unsigned)(t + 1));
  }
  cbuf[bq * H + bk * 16 + jl] = c_s[tid];
}

// ---------------- persistent decoder: 32 blocks x 512 ----------------------
// Block bk: full attention for batch bk + LSTM for j-cols [bk*16,+16) all B.
// gates_h hoisted before attention; gates_w B-frags register-cached.
__global__ __launch_bounds__(512) void dec_persist32(
    unsigned* fhs, unsigned* fws, const float* __restrict__ fc_w,
    const float* __restrict__ fc_b, const u16* __restrict__ wdec_p,
    const u16* __restrict__ a1T_bf, const float* __restrict__ attn_v,
    const int* __restrict__ src, const u16* __restrict__ hf_bf,
    const float* __restrict__ cbuf, const u16* __restrict__ epart_bf,
    const u16* __restrict__ enc_bt_bf, const float* __restrict__ eih_p,
    u16* hstep, u16* wstep, u16* __restrict__ xout_bf) {
  __shared__ float buf[8][512];   // attn partials
  __shared__ float hs[512], hps[512];
  __shared__ float gh[32][64];    // gates h-part
  __shared__ float gw[32][64];    // gates w-part
  __shared__ float sc[128], red[2];
  __shared__ int smask[128];
  __shared__ float c_s[512];
  __shared__ u16 hx[512];
  const int tid = threadIdx.x, bk = blockIdx.x;
  const int wave = tid >> 6, lane = tid & 63;
  const int lr = lane & 15, lk = lane >> 4;
  const int bq = tid >> 4, jl = tid & 15;
  c_s[tid] = cbuf[bq * H + bk * 16 + jl];
  if (tid < 128) smask[tid] = src[bk * S + tid];
  float av8[8];
#pragma unroll
  for (int e = 0; e < 8; e++) av8[e] = attn_v[lane * 8 + e];
  // fc: hidden = tanh(hf @ fc_w^T + fc_b) -> h[0] slice (waves 0,1)
  if (wave < 2) {
    const u16* ab = hf_bf + (size_t)(wave * 16 + lr) * H + lk * 8;
    const float* frow = fc_w + (size_t)(bk * 16 + lr) * H + lk * 8;
    f32x4 acc = {};
#pragma unroll
    for (int kt = 0; kt < 16; kt++) {
      bf16x8 a = *(const bf16x8*)(ab + kt * 32);
      bf16x8 w;
#pragma unroll
      for (int e = 0; e < 8; e++) w[e] = (short)f2bf(frow[kt * 32 + e]);
      acc = MFMA(a, w, acc, 0, 0, 0);
    }
    float bs = fc_b[bk * 16 + lr];
#pragma unroll
    for (int rr = 0; rr < 4; rr++)
      hx[(wave * 16 + lk * 4 + rr) * 16 + lr] = f2bf(tanh_(acc[rr] + bs));
  }
  __syncthreads();
  {
    u64 kp = 0;
    if (tid < 128) {
      int bb = tid >> 2, q = tid & 3;
      kp = xstore(hstep + (size_t)bb * H + bk * 16 + q * 4,
                  pack4u(&hx[bb * 16 + q * 4]));
    }
    if (wave < 2) {
      asm volatile("" :: "v"(kp));
      asm volatile("s_waitcnt vmcnt(0)" ::: "memory");
    }
    __syncthreads();
    if (tid == 0) sstore(fhs + bk * 16, 1u);
  }
  // gate weight slice pointers; register-cache the w-part (post-poll path)
  const int mt = wave & 1, nt = wave >> 1;
  const int n = nt * 16 + lr;
  const u16* wpw = wdec_p + (size_t)(bk * 64 + n) * 1024 + lk * 8;
  const u16* wph = wpw + 512;
  bf16x8 wwf[16];
#pragma unroll
  for (int kt = 0; kt < 16; kt++) wwf[kt] = *(const bf16x8*)(wpw + kt * 32);
  // ---- time loop ----
  for (int t = 0; t < TD; t++) {
    if (tid < 32) poll_bo(fhs + tid * 16, (unsigned)(t + 1));
    __syncthreads();
    float4 xv = *(const float4*)(eih_p + ((size_t)t * B + bq) * H4 +
                                 (bk * 16 + jl) * 4);
    // --- gates_h FIRST (needs only h[t]; off the post-w-poll path) ---
    {
      const u16* ah =
          hstep + (size_t)t * B * H + (size_t)(mt * 16 + lr) * H + lk * 8;
      f32x4 acc = {};
#pragma unroll
      for (int kt = 0; kt < 16; kt++) {
        bf16x8 a = *(const bf16x8*)(ah + kt * 32);
        bf16x8 w = *(const bf16x8*)(wph + kt * 32);
        acc = MFMA(a, w, acc, 0, 0, 0);
      }
#pragma unroll
      for (int rr = 0; rr < 4; rr++) gh[mt * 16 + lk * 4 + rr][n] = acc[rr];
    }
    // --- attention for own batch bk ---
    if (tid < 256) {
      u32 v = ((const u32*)(hstep + (size_t)t * B * H + (size_t)bk * H))[tid];
      hs[2 * tid] = bf2f((u16)(v & 0xffff));
      hs[2 * tid + 1] = bf2f((u16)(v >> 16));
    }
    __syncthreads();
    {  // hp partials: wave w covers k in [w*64, w*64+64)
      float p[8] = {};
      const int j0 = lane * 8;
#pragma unroll 8
      for (int kk = 0; kk < 64; kk++) {
        int k = wave * 64 + kk;
        float hk = hs[k];
        u16x8 av = *(const u16x8*)&a1T_bf[(size_t)k * H + j0];
#pragma unroll
        for (int e = 0; e < 8; e++) p[e] += hk * bf2f(av[e]);
      }
#pragma unroll
      for (int e = 0; e < 8; e++) buf[wave][j0 + e] = p[e];
    }
    __syncthreads();
    {
      float s0 = 0.f;
#pragma unroll
      for (int w = 0; w < 8; w++) s0 += buf[w][tid];
      hps[tid] = s0;
    }
    __syncthreads();
    {  // scores: wave w covers s in [w*16, w*16+16)
      const int j0 = lane * 8;
      float hp8[8];
#pragma unroll
      for (int e = 0; e < 8; e++) hp8[e] = hps[j0 + e];
#pragma unroll 4
      for (int i = 0; i < 16; i++) {
        int s = wave * 16 + i;
        u16x8 ep = *(const u16x8*)&epart_bf[((size_t)bk * S + s) * H + j0];
        float a = 0.f;
#pragma unroll
        for (int e = 0; e < 8; e++) a += av8[e] * tanhf_(hp8[e] + bf2f(ep[e]));
#pragma unroll
        for (int o = 32; o; o >>= 1) a += __shfl_xor(a, o);
        if (lane == 0) sc[s] = (smask[s] == PAD_IDX) ? -1e10f : a;
      }
    }
    __syncthreads();
    if (tid < 64) {
      float v = fmaxf(sc[tid], sc[tid + 64]);
#pragma unroll
      for (int o = 32; o; o >>= 1) v = fmaxf(v, __shfl_xor(v, o));
      if (tid == 0) red[0] = v;
    }
    __syncthreads();
    float mx = red[0];
    if (tid < S) sc[tid] = __expf(sc[tid] - mx);
    __syncthreads();
    if (tid < 64) {
      float v = sc[tid] + sc[tid + 64];
#pragma unroll
      for (int o = 32; o; o >>= 1) v += __shfl_xor(v, o);
      if (tid == 0) red[1] = 1.f / v;
    }
    __syncthreads();
    {  // weighted partials: wave w owns s in [w*16, w*16+16)
      float acc8[8] = {};
      const int j0 = lane * 8;
#pragma unroll 4
      for (int i = 0; i < 16; i++) {
        int s = wave * 16 + i;
        float ps = sc[s];
        u16x8 ev = *(const u16x8*)&enc_bt_bf[((size_t)bk * S + s) * H + j0];
#pragma unroll
        for (int e = 0; e < 8; e++) acc8[e] += ps * bf2f(ev[e]);
      }
#pragma unroll
      for (int e = 0; e < 8; e++) buf[wave][j0 + e] = acc8[e];
    }
    __syncthreads();
    {  // finalize + publish w (own batch)
      u64 kp = 0;
      if (tid < 128) {
        float inv = red[1];
        int j0 = tid * 4;
        u16x4 o;
#pragma unroll
        for (int i = 0; i < 4; i++) {
          float wj = (buf[0][j0 + i] + buf[1][j0 + i] + buf[2][j0 + i] +
                      buf[3][j0 + i] + buf[4][j0 + i] + buf[5][j0 + i] +
                      buf[6][j0 + i] + buf[7][j0 + i]) *
                     inv;
          o[i] = f2bf(wj);
        }
        *(u16x4*)&xout_bf[((size_t)t * B + bk) * KOUT + H + j0] = o;
        u64 val = (u64)o[0] | ((u64)o[1] << 16) | ((u64)o[2] << 32) |
                  ((u64)o[3] << 48);
        kp = xstore(wstep + ((size_t)t * B + bk) * H + j0, val);
      }
      if (wave < 2) {
        asm volatile("" :: "v"(kp));
        asm volatile("s_waitcnt vmcnt(0)" ::: "memory");
      }
      __syncthreads();
      if (tid == 0) sstore(fws + bk * 16, (unsigned)(t + 1));
    }
    // --- gates_w: M=32, N=64, K=512 (w only; B-frags in registers) ---
    if (tid < 32) poll_bo(fws + tid * 16, (unsigned)(t + 1));
    __syncthreads();
    {
      const u16* aw =
          wstep + (size_t)t * B * H + (size_t)(mt * 16 + lr) * H + lk * 8;
      f32x4 acc = {};
#pragma unroll
      for (int kt = 0; kt < 16; kt++) {
        bf16x8 a = *(const bf16x8*)(aw + kt * 32);
        acc = MFMA(a, wwf[kt], acc, 0, 0, 0);
      }
#pragma unroll
      for (int rr = 0; rr < 4; rr++) gw[mt * 16 + lk * 4 + rr][n] = acc[rr];
    }
    __syncthreads();
    {  // pointwise
      float gi = xv.x + gh[bq][jl * 4 + 0] + gw[bq][jl * 4 + 0];
      float gf = xv.y + gh[bq][jl * 4 + 1] + gw[bq][jl * 4 + 1];
      float gg = xv.z + gh[bq][jl * 4 + 2] + gw[bq][jl * 4 + 2];
      float go = xv.w + gh[bq][jl * 4 + 3] + gw[bq][jl * 4 + 3];
      float cn = sigm(gf) * c_s[tid] + sigm(gi) * tanh_(gg);
      c_s[tid] = cn;
      u16 h16 = f2bf(sigm(go) * tanh_(cn));
      hx[tid] = h16;
      xout_bf[((size_t)t * B + bq) * KOUT + bk * 16 + jl] = h16;
    }
    __syncthreads();
    {  // publish h slice
      u64 kp = 0;
      if (tid < 128) {
        int bb = tid >> 2, q = tid & 3;
        kp = xstore(hstep + (size_t)(t + 1) * B * H + (size_t)bb * H +
                        bk * 16 + q * 4,
                    pack4u(&hx[bb * 16 + q * 4]));
      }
      if (wave < 2) {
        asm volatile("" :: "v"(kp));
        asm volatile("s_waitcnt vmcnt(0)" ::: "memory");
      }
      __syncthreads();
      if (tid == 0) sstore(fhs + bk * 16, (unsigned)(t + 2));
    }
  }
}

// ---------------------------------------------------------------------------
extern "C" void kernel_launch(void* const* d_in, const int* in_sizes, int n_in,
                              void* d_out, int out_size, void* d_ws,
                              size_t ws_size, hipStream_t stream) {
  const int* src = (const int*)d_in[0];
  const int* trg = (const int*)d_in[2];
  const float* enc_emb = (const float*)d_in[3];
  const float* enc_wih = (const float*)d_in[4];
  const float* enc_whh = (const float*)d_in[5];
  const float* enc_bih = (const float*)d_in[6];
  const float* enc_bhh = (const float*)d_in[7];
  const float* fc_w = (const float*)d_in[8];
  const float* fc_b = (const float*)d_in[9];
  const float* dec_emb = (const float*)d_in[10];
  const float* attn_w = (const float*)d_in[11];
  const float* attn_b = (const float*)d_in[12];
  const float* attn_v = (const float*)d_in[13];
  const float* dec_wih = (const float*)d_in[14];
  const float* dec_whh = (const float*)d_in[15];
  const float* dec_bih = (const float*)d_in[16];
  const float* dec_bhh = (const float*)d_in[17];
  const float* out_w = (const float*)d_in[18];
  const float* out_b = (const float*)d_in[19];
  float* out = (float*)d_out;

  char* wp = (char*)d_ws;
  auto alloc = [&](size_t n) {
    char* p = wp;
    wp += (n + 255) & ~(size_t)255;
    return p;
  };
  u16* outw_bf = (u16*)alloc((size_t)V * KOUT * 2);        // 98.3 MB
  u16* wihenc_p = (u16*)alloc((size_t)H4 * H * 2);         // 2.1 MB
  u16* wihE_p = (u16*)alloc((size_t)H4 * H * 2);           // 2.1 MB
  u16* wenc_p = (u16*)alloc((size_t)H4 * H * 2);           // 2.1 MB
  u16* wdec_p = (u16*)alloc((size_t)H4 * 2 * H * 2);       // 8.4 MB
  u16* attnw2_bf = (u16*)alloc((size_t)H * H * 2);         // 0.5 MB
  u16* a1T_bf = (u16*)alloc((size_t)H * H * 2);            // 0.5 MB
  u16* xemb_bf = (u16*)alloc((size_t)S * B * H * 2);       // 4.2 MB
  float* xih_p = (float*)alloc((size_t)S * B * H4 * 4);    // 33.6 MB
  u16* enc_bt_bf = (u16*)alloc((size_t)B * S * H * 2);     // 4.2 MB
  u16* epart_bf = (u16*)alloc((size_t)B * S * H * 2);      // 4.2 MB
  float* eih_p = (float*)alloc((size_t)MOUT * H4 * 4);     // 16.5 MB
  u16* xout_bf = (u16*)alloc((size_t)MOUT * KOUT * 2);     // 6.2 MB
  u16* hstep_enc = (u16*)alloc((size_t)(S + 1) * B * H * 2);  // 4.3 MB
  u16* hstep_dec = (u16*)alloc((size_t)T * B * H * 2);        // 2.1 MB
  u16* wstep = (u16*)alloc((size_t)TD * B * H * 2);           // 2.1 MB
  float* cbuf = (float*)alloc((size_t)B * H * 4);
  float* benc_p = (float*)alloc((size_t)H4 * 4);
  float* bdec_p = (float*)alloc((size_t)H4 * 4);
  unsigned* flags = (unsigned*)alloc(2048 * 4);
  unsigned* fes = flags;            // 32 slots x 16 u32
  unsigned* fhs = flags + 512;      // 32 slots x 16 u32
  unsigned* fws = flags + 1024;     // 32 slots x 16 u32

  dim3 blk(256);
  zero_f<<<dim3(256), blk, 0, stream>>>(out, (long)B * V);
  zero_u<<<dim3(8), blk, 0, stream>>>(flags, 2048);
  zero_u<<<dim3(32), blk, 0, stream>>>((unsigned*)hstep_enc, B * H / 2);
  // weight preparation
  cast_bf4<<<dim3(((long)V * KOUT / 4 + 255) / 256), blk, 0, stream>>>(
      out_w, outw_bf, (long)V * KOUT / 4);
  cast_perm<<<dim3(H / 256, H4), blk, 0, stream>>>(enc_wih, H, 0, wihenc_p);
  cast_perm<<<dim3(H / 256, H4), blk, 0, stream>>>(dec_wih, 2 * H, 0, wihE_p);
  cast_perm<<<dim3(H / 256, H4), blk, 0, stream>>>(enc_whh, H, 0, wenc_p);
  pack_wdec_p<<<dim3(4, H4), blk, 0, stream>>>(dec_wih, dec_whh, wdec_p);
  cast_bf<<<dim3(H / 256, H), blk, 0, stream>>>(attn_w, attnw2_bf, 2 * H, H, H);
  cast_transpose_bf<<<dim3(H / 32, H / 32), blk, 0, stream>>>(attn_w, 2 * H, 0,
                                                              a1T_bf, H);
  bias_perm<<<dim3(H4 / 256), blk, 0, stream>>>(enc_bih, enc_bhh, benc_p);
  bias_perm<<<dim3(H4 / 256), blk, 0, stream>>>(dec_bih, dec_bhh, bdec_p);
  gather_src_emb<<<dim3(H / 256, S * B), blk, 0, stream>>>(src, enc_emb,
                                                           xemb_bf);
  gather_trg_emb<<<dim3(H / 256, MOUT), blk, 0, stream>>>(trg, dec_emb,
                                                          xout_bf);
  // input-side GEMMs (permuted cols, biases folded)
  gemm_bt<<<dim3(H4 / 128, (S * B) / 128), blk, 0, stream>>>(
      xemb_bf, H, wihenc_p, H, xih_p, H4, benc_p, S * B, H, 0);
  gemm_bt<<<dim3(H4 / 128, (MOUT + 127) / 128), blk, 0, stream>>>(
      xout_bf + 2 * H, KOUT, wihE_p, H, eih_p, H4, bdec_p, MOUT, H, 0);
  // persistent encoder
  enc_persist32<<<dim3(32), dim3(512), 0, stream>>>(fes, wenc_p, xih_p,
                                                    hstep_enc, enc_bt_bf, cbuf);
  // epart = enc_bt @ attn_w2^T + attn_b  (bf16 out)
  gemm_bt<<<dim3(H / 128, (B * S) / 128), blk, 0, stream>>>(
      enc_bt_bf, H, attnw2_bf, H, (float*)epart_bf, H, attn_b, B * S, H, 1);
  // persistent decoder (h_f = hstep_enc step S)
  dec_persist32<<<dim3(32), dim3(512), 0, stream>>>(
      fhs, fws, fc_w, fc_b, wdec_p, a1T_bf, attn_v, src,
      hstep_enc + (size_t)S * B * H, cbuf, epart_bf, enc_bt_bf, eih_p,
      hstep_dec, wstep, xout_bf);
  // final logits GEMM
  gemm_bt<<<dim3(V / 128, (MOUT + 127) / 128), blk, 0, stream>>>(
      xout_bf, KOUT, outw_bf, KOUT, out + (size_t)B * V, V, out_b, MOUT, KOUT,
      0);
}

// Round 11
// 2934.153 us; speedup vs baseline: 7.2029x; 1.0844x over previous
//
#include <hip/hip_runtime.h>

typedef unsigned short u16;
typedef unsigned int u32;
typedef unsigned long long u64;
typedef __attribute__((ext_vector_type(8))) short bf16x8;
typedef __attribute__((ext_vector_type(8))) unsigned short u16x8;
typedef __attribute__((ext_vector_type(4))) unsigned short u16x4;
typedef __attribute__((ext_vector_type(4))) float f32x4;

#define DEVI static __device__ __forceinline__
#define MFMA __builtin_amdgcn_mfma_f32_16x16x32_bf16

constexpr int B = 32, S = 128, T = 64, H = 512, V = 32000;
constexpr int H4 = 4 * H;          // 2048
constexpr int TD = T - 1;          // 63 decoder steps
constexpr int MOUT = TD * B;       // 2016
constexpr int KOUT = 3 * H;        // 1536
constexpr int PAD_IDX = 1;

DEVI u16 f2bf(float f) {
  union { float f; unsigned u; } v; v.f = f;
  unsigned r = (v.u + 0x7fffu + ((v.u >> 16) & 1u)) >> 16;
  return (u16)r;
}
DEVI float bf2f(u16 h) {
  union { unsigned u; float f; } v; v.u = ((unsigned)h) << 16;
  return v.f;
}
DEVI float sigm(float x) { return 1.f / (1.f + __expf(-x)); }
DEVI float tanh_(float x) {
  float ax = fabsf(x);
  float e = __expf(-2.f * ax);
  float t = (1.f - e) / (1.f + e);
  return x < 0.f ? -t : t;
}
DEVI float tanhf_(float x) {
  float e = __expf(2.f * x);
  return 1.f - 2.f * __builtin_amdgcn_rcpf(e + 1.f);
}
DEVI int swz(int row, int k8) { return row * 32 + ((k8 ^ (row & 3)) << 3); }

DEVI u64 pack4u(const u16* p) {
  return (u64)p[0] | ((u64)p[1] << 16) | ((u64)p[2] << 32) | ((u64)p[3] << 48);
}
// data write-through to coherence point; returned old keeps vmcnt honest
DEVI u64 xstore(u16* p, u64 v) {
  return __hip_atomic_exchange((u64*)p, v, __ATOMIC_RELAXED,
                               __HIP_MEMORY_SCOPE_AGENT);
}
DEVI u64 xstore64(u64* p, u64 v) {
  return __hip_atomic_exchange(p, v, __ATOMIC_RELAXED,
                               __HIP_MEMORY_SCOPE_AGENT);
}
DEVI void sstore(unsigned* p, unsigned v) {
  __hip_atomic_exchange(p, v, __ATOMIC_RELAXED, __HIP_MEMORY_SCOPE_AGENT);
}
// poll with light backoff; loads only, 64B-strided slots
DEVI void poll_bo(unsigned* p, unsigned tgt) {
  int it = 0;
  long long t0 = (long long)__builtin_amdgcn_s_memrealtime();
  while (__hip_atomic_load(p, __ATOMIC_RELAXED, __HIP_MEMORY_SCOPE_AGENT) <
         tgt) {
    if (it < 4) {
      __builtin_amdgcn_s_sleep(1);
      it++;
    } else {
      __builtin_amdgcn_s_sleep(4);
    }
    if ((long long)__builtin_amdgcn_s_memrealtime() - t0 > 20000000ll) break;
  }
}

// ---------------- bf16 MFMA GEMM (256-thr standalone) ----------------------
__global__ __launch_bounds__(256) void gemm_bt(
    const u16* __restrict__ A, int lda,
    const u16* __restrict__ Bt, int ldb,
    float* __restrict__ C, int ldc,
    const float* __restrict__ bias, int M, int K, int bf16out) {
  __shared__ u16 As[128 * 32], Bs[128 * 32];
  const int tid = threadIdx.x;
  const int m0 = blockIdx.y * 128, n0 = blockIdx.x * 128;
  const int lane = tid & 63, w = tid >> 6, wm = w >> 1, wn = w & 1;
  const int lr = lane & 15, lk = lane >> 4;
  f32x4 acc[4][4] = {};
  const int r = tid >> 1, cc = (tid & 1) * 16, k8b = (tid & 1) * 2;

  for (int k0 = 0; k0 < K; k0 += 32) {
    {
      long gr = m0 + r;
      u16x8 v0 = {}, v1 = {};
      if (gr < M) {
        const u16* s = A + gr * (long)lda + k0 + cc;
        v0 = *(const u16x8*)s;
        v1 = *(const u16x8*)(s + 8);
      }
      *(u16x8*)&As[swz(r, k8b)] = v0;
      *(u16x8*)&As[swz(r, k8b + 1)] = v1;
    }
    {
      const u16* s = Bt + (long)(n0 + r) * ldb + k0 + cc;
      u16x8 v0 = *(const u16x8*)s;
      u16x8 v1 = *(const u16x8*)(s + 8);
      *(u16x8*)&Bs[swz(r, k8b)] = v0;
      *(u16x8*)&Bs[swz(r, k8b + 1)] = v1;
    }
    __syncthreads();
    bf16x8 af[4], bfr[4];
#pragma unroll
    for (int mi = 0; mi < 4; mi++)
      af[mi] = *(const bf16x8*)&As[swz(wm * 64 + mi * 16 + lr, lk)];
#pragma unroll
    for (int ni = 0; ni < 4; ni++)
      bfr[ni] = *(const bf16x8*)&Bs[swz(wn * 64 + ni * 16 + lr, lk)];
#pragma unroll
    for (int mi = 0; mi < 4; mi++)
#pragma unroll
      for (int ni = 0; ni < 4; ni++)
        acc[mi][ni] = MFMA(af[mi], bfr[ni], acc[mi][ni], 0, 0, 0);
    __syncthreads();
  }
#pragma unroll
  for (int ni = 0; ni < 4; ni++) {
    int col = n0 + wn * 64 + ni * 16 + lr;
    float bs = bias ? bias[col] : 0.f;
#pragma unroll
    for (int mi = 0; mi < 4; mi++) {
#pragma unroll
      for (int rr = 0; rr < 4; rr++) {
        long row = m0 + wm * 64 + mi * 16 + lk * 4 + rr;
        if (row < M) {
          float v = acc[mi][ni][rr] + bs;
          if (bf16out)
            ((u16*)C)[row * (long)ldc + col] = f2bf(v);
          else
            C[row * (long)ldc + col] = v;
        }
      }
    }
  }
}

// 512-thread variant (threads 256..511 idle but join barriers)
DEVI void gemm_tile512(const u16* A, int lda, const u16* Bt, int ldb,
                       float* C, int ldc, const float* bias, int M, int K,
                       int mt, int nt) {
  __shared__ u16 As[128 * 32], Bs[128 * 32];
  const int tid = threadIdx.x;
  const bool act = tid < 256;
  const int m0 = mt * 128, n0 = nt * 128;
  const int lane = tid & 63, w = tid >> 6, wm = (w >> 1) & 1, wn = w & 1;
  const int lr = lane & 15, lk = lane >> 4;
  f32x4 acc[4][4] = {};
  const int r = (tid >> 1) & 127, cc = (tid & 1) * 16, k8b = (tid & 1) * 2;

  for (int k0 = 0; k0 < K; k0 += 32) {
    if (act) {
      {
        long gr = m0 + r;
        u16x8 v0 = {}, v1 = {};
        if (gr < M) {
          const u16* s = A + gr * (long)lda + k0 + cc;
          v0 = *(const u16x8*)s;
          v1 = *(const u16x8*)(s + 8);
        }
        *(u16x8*)&As[swz(r, k8b)] = v0;
        *(u16x8*)&As[swz(r, k8b + 1)] = v1;
      }
      {
        const u16* s = Bt + (long)(n0 + r) * ldb + k0 + cc;
        u16x8 v0 = *(const u16x8*)s;
        u16x8 v1 = *(const u16x8*)(s + 8);
        *(u16x8*)&Bs[swz(r, k8b)] = v0;
        *(u16x8*)&Bs[swz(r, k8b + 1)] = v1;
      }
    }
    __syncthreads();
    if (act) {
      bf16x8 af[4], bfr[4];
#pragma unroll
      for (int mi = 0; mi < 4; mi++)
        af[mi] = *(const bf16x8*)&As[swz(wm * 64 + mi * 16 + lr, lk)];
#pragma unroll
      for (int ni = 0; ni < 4; ni++)
        bfr[ni] = *(const bf16x8*)&Bs[swz(wn * 64 + ni * 16 + lr, lk)];
#pragma unroll
      for (int mi = 0; mi < 4; mi++)
#pragma unroll
        for (int ni = 0; ni < 4; ni++)
          acc[mi][ni] = MFMA(af[mi], bfr[ni], acc[mi][ni], 0, 0, 0);
    }
    __syncthreads();
  }
  if (act) {
#pragma unroll
    for (int ni = 0; ni < 4; ni++) {
      int col = n0 + wn * 64 + ni * 16 + lr;
      float bs = bias ? bias[col] : 0.f;
#pragma unroll
      for (int mi = 0; mi < 4; mi++) {
#pragma unroll
        for (int rr = 0; rr < 4; rr++) {
          long row = m0 + wm * 64 + mi * 16 + lk * 4 + rr;
          if (row < M) C[row * (long)ldc + col] = acc[mi][ni][rr] + bs;
        }
      }
    }
  }
}

// ---------------- helpers ---------------------------------------------------
__global__ void zero_f(float* p, long n) {
  long i = (long)blockIdx.x * 256 + threadIdx.x;
  long st = (long)gridDim.x * 256;
  for (; i < n; i += st) p[i] = 0.f;
}

__global__ void zero_u(unsigned* p, int n) {
  int i = blockIdx.x * 256 + threadIdx.x;
  if (i < n) p[i] = 0u;
}

__global__ void cast_bf(const float* __restrict__ src, u16* __restrict__ dst,
                        int ld, int off, int Csz) {
  long row = blockIdx.y;
  int col = blockIdx.x * 256 + threadIdx.x;
  dst[row * Csz + col] = f2bf(src[row * ld + off + col]);
}

// permuted-row cast: dst row n' = src row (g*H + jH), n' = jH*4 + g
__global__ void cast_perm(const float* __restrict__ src, int ld, int off,
                          u16* __restrict__ dst) {
  int np = blockIdx.y;
  int c = blockIdx.x * 256 + threadIdx.x;
  int g = np & 3, jH = np >> 2;
  dst[(size_t)np * H + c] = f2bf(src[(size_t)(g * H + jH) * ld + off + c]);
}

// wdec_p row r = j*4+g, cols [0:512)=wih weighted-part, [512:1024)=whh
__global__ void pack_wdec_p(const float* __restrict__ wih,
                            const float* __restrict__ whh,
                            u16* __restrict__ dst) {
  int r = blockIdx.y;
  int k = blockIdx.x * 256 + threadIdx.x;
  int g = r & 3, j = r >> 2;
  int srow = g * H + j;
  float v = (k < 512) ? wih[(size_t)srow * (2 * H) + 512 + k]
                      : whh[(size_t)srow * H + (k - 512)];
  dst[(size_t)r * 1024 + k] = f2bf(v);
}

__global__ void bias_perm(const float* __restrict__ a,
                          const float* __restrict__ b, float* __restrict__ o) {
  int np = blockIdx.x * 256 + threadIdx.x;
  int g = np & 3, jH = np >> 2;
  int r = g * H + jH;
  o[np] = a[r] + b[r];
}

__global__ void gather_src_emb(const int* __restrict__ src,
                               const float* __restrict__ emb,
                               u16* __restrict__ dst) {
  int row = blockIdx.y;           // row = t*B + b
  int t = row >> 5, b = row & 31;
  int c = blockIdx.x * 256 + threadIdx.x;
  int tok = src[b * S + t];
  dst[(long)row * H + c] = f2bf(emb[(long)tok * H + c]);
}

__global__ void gather_trg_emb(const int* __restrict__ trg,
                               const float* __restrict__ emb,
                               u16* __restrict__ xout) {
  int row = blockIdx.y;           // row = t*B + b, t < 63
  int t = row >> 5, b = row & 31;
  int c = blockIdx.x * 256 + threadIdx.x;
  int tok = trg[b * T + t];
  xout[(long)row * KOUT + 2 * H + c] = f2bf(emb[(long)tok * H + c]);
}

// ---------------- fused encoder launch --------------------------------------
// blocks 0..31: persistent encoder (as r10). blocks 32..287: eih GEMM tiles
// (consumed by later dec kernel -> normal stores OK). blocks 288..383: outw
// cast (consumed by later final GEMM). All 384 blocks co-resident (2/CU).
__global__ __launch_bounds__(512) void enc_fused(
    unsigned* fes, const u16* __restrict__ wenc_p,
    const float* __restrict__ xih_p, u16* hstep, u16* enc_bt_bf, float* cbuf,
    const u16* __restrict__ xoute, const u16* __restrict__ wihE_p,
    float* __restrict__ eih_p, const float* __restrict__ bdec_p,
    const float* __restrict__ out_w, u16* __restrict__ outw_bf) {
  const int bk = blockIdx.x;
  if (bk >= 288) {  // outw cast, grid-stride
    long i = (long)(bk - 288) * 512 + threadIdx.x;
    const long n4 = (long)V * KOUT / 4, st = 96L * 512;
    for (; i < n4; i += st) {
      float4 v = ((const float4*)out_w)[i];
      u16x4 o;
      o[0] = f2bf(v.x); o[1] = f2bf(v.y); o[2] = f2bf(v.z); o[3] = f2bf(v.w);
      *(u16x4*)&outw_bf[i * 4] = o;
    }
    return;
  }
  if (bk >= 32) {  // eih = xout_e @ wihE_p^T + bdec_p
    int job = bk - 32, mt = job >> 4, nt = job & 15;
    gemm_tile512(xoute, KOUT, wihE_p, H, eih_p, H4, bdec_p, MOUT, H, mt, nt);
    return;
  }
  // ---- persistent encoder block ----
  __shared__ float gs[32][64];
  __shared__ float c_s[512];
  __shared__ u16 hx[512];
  const int tid = threadIdx.x;
  const int wave = tid >> 6, lane = tid & 63;
  const int lr = lane & 15, lk = lane >> 4;
  const int bq = tid >> 4, jl = tid & 15;
  c_s[tid] = 0.f;
  const int mt = wave & 1, nt = wave >> 1;
  const int n = nt * 16 + lr;
  bf16x8 wf[16];
  {
    const u16* wp = wenc_p + (size_t)(bk * 64 + n) * 512 + lk * 8;
#pragma unroll
    for (int kt = 0; kt < 16; kt++) wf[kt] = *(const bf16x8*)(wp + kt * 32);
  }
  for (int t = 0; t < S; t++) {
    if (t > 0 && tid < 32) poll_bo(fes + tid * 16, (unsigned)t);
    __syncthreads();
    float4 xv = *(const float4*)(xih_p + ((size_t)t * B + bq) * H4 +
                                 (bk * 16 + jl) * 4);
    {
      const u16* ab =
          hstep + (size_t)t * B * H + (size_t)(mt * 16 + lr) * H + lk * 8;
      f32x4 acc = {};
#pragma unroll
      for (int kt = 0; kt < 16; kt++) {
        bf16x8 a = *(const bf16x8*)(ab + kt * 32);
        acc = MFMA(a, wf[kt], acc, 0, 0, 0);
      }
#pragma unroll
      for (int rr = 0; rr < 4; rr++) gs[mt * 16 + lk * 4 + rr][n] = acc[rr];
    }
    __syncthreads();
    {
      float gi = xv.x + gs[bq][jl * 4 + 0];
      float gf = xv.y + gs[bq][jl * 4 + 1];
      float gg = xv.z + gs[bq][jl * 4 + 2];
      float go = xv.w + gs[bq][jl * 4 + 3];
      float cn = sigm(gf) * c_s[tid] + sigm(gi) * tanh_(gg);
      c_s[tid] = cn;
      u16 h16 = f2bf(sigm(go) * tanh_(cn));
      hx[tid] = h16;
      enc_bt_bf[((size_t)bq * S + t) * H + bk * 16 + jl] = h16;
    }
    __syncthreads();
    u64 kp = 0;
    if (tid < 128) {
      int bb = tid >> 2, q = tid & 3;
      kp = xstore(hstep + (size_t)(t + 1) * B * H + (size_t)bb * H + bk * 16 +
                      q * 4,
                  pack4u(&hx[bb * 16 + q * 4]));
    }
    if (wave < 2) {
      asm volatile("" :: "v"(kp));
      asm volatile("s_waitcnt vmcnt(0)" ::: "memory");
    }
    __syncthreads();
    if (tid == 0) sstore(fes + bk * 16, (unsigned)(t + 1));
  }
  cbuf[bq * H + bk * 16 + jl] = c_s[tid];
}

// ---------------- persistent decoder: 32 blocks x 512 ----------------------
// Block bk: attention for batch bk + LSTM j-cols [bk*16,+16) + hp n-shard.
// hp = h @ a1^T computed as sharded MFMA (16 KB a1-slice vs 512 KB stream),
// exchanged via hpstep (f32) with fps flags.
__global__ __launch_bounds__(512) void dec_persist32(
    unsigned* fhs, unsigned* fws, unsigned* fps, const float* __restrict__ fc_w,
    const float* __restrict__ fc_b, const u16* __restrict__ wdec_p,
    const u16* __restrict__ a1_bf, const float* __restrict__ attn_v,
    const int* __restrict__ src, const u16* __restrict__ hf_bf,
    const float* __restrict__ cbuf, const u16* __restrict__ epart_bf,
    const u16* __restrict__ enc_bt_bf, const float* __restrict__ eih_p,
    u16* hstep, u16* wstep, float* hpstep, u16* __restrict__ xout_bf) {
  __shared__ float buf[8][512];   // weighted partials
  __shared__ float hps[512];
  __shared__ float hp2[32][16];
  __shared__ float gh[32][64];
  __shared__ float gw[32][64];
  __shared__ float sc[128], red[2];
  __shared__ int smask[128];
  __shared__ float c_s[512];
  __shared__ u16 hx[512];
  const int tid = threadIdx.x, bk = blockIdx.x;
  const int wave = tid >> 6, lane = tid & 63;
  const int lr = lane & 15, lk = lane >> 4;
  const int bq = tid >> 4, jl = tid & 15;
  c_s[tid] = cbuf[bq * H + bk * 16 + jl];
  if (tid < 128) smask[tid] = src[bk * S + tid];
  float av8[8];
#pragma unroll
  for (int e = 0; e < 8; e++) av8[e] = attn_v[lane * 8 + e];
  // fc: hidden = tanh(hf @ fc_w^T + fc_b) -> h[0] slice (waves 0,1)
  if (wave < 2) {
    const u16* ab = hf_bf + (size_t)(wave * 16 + lr) * H + lk * 8;
    const float* frow = fc_w + (size_t)(bk * 16 + lr) * H + lk * 8;
    f32x4 acc = {};
#pragma unroll
    for (int kt = 0; kt < 16; kt++) {
      bf16x8 a = *(const bf16x8*)(ab + kt * 32);
      bf16x8 w;
#pragma unroll
      for (int e = 0; e < 8; e++) w[e] = (short)f2bf(frow[kt * 32 + e]);
      acc = MFMA(a, w, acc, 0, 0, 0);
    }
    float bs = fc_b[bk * 16 + lr];
#pragma unroll
    for (int rr = 0; rr < 4; rr++)
      hx[(wave * 16 + lk * 4 + rr) * 16 + lr] = f2bf(tanh_(acc[rr] + bs));
  }
  __syncthreads();
  {
    u64 kp = 0;
    if (tid < 128) {
      int bb = tid >> 2, q = tid & 3;
      kp = xstore(hstep + (size_t)bb * H + bk * 16 + q * 4,
                  pack4u(&hx[bb * 16 + q * 4]));
    }
    if (wave < 2) {
      asm volatile("" :: "v"(kp));
      asm volatile("s_waitcnt vmcnt(0)" ::: "memory");
    }
    __syncthreads();
    if (tid == 0) sstore(fhs + bk * 16, 1u);
  }
  // gate weight slices; register-cache the w-part (post-poll path)
  const int mt = wave & 1, nt = wave >> 1;
  const int n = nt * 16 + lr;
  const u16* wpw = wdec_p + (size_t)(bk * 64 + n) * 1024 + lk * 8;
  const u16* wph = wpw + 512;
  bf16x8 wwf[16];
#pragma unroll
  for (int kt = 0; kt < 16; kt++) wwf[kt] = *(const bf16x8*)(wpw + kt * 32);
  // ---- time loop ----
  for (int t = 0; t < TD; t++) {
    if (tid < 32) poll_bo(fhs + tid * 16, (unsigned)(t + 1));
    __syncthreads();
    float4 xv = *(const float4*)(eih_p + ((size_t)t * B + bq) * H4 +
                                 (bk * 16 + jl) * 4);
    // --- gates_h (all waves) ---
    {
      const u16* ah =
          hstep + (size_t)t * B * H + (size_t)(mt * 16 + lr) * H + lk * 8;
      f32x4 acc = {};
#pragma unroll
      for (int kt = 0; kt < 16; kt++) {
        bf16x8 a = *(const bf16x8*)(ah + kt * 32);
        bf16x8 w = *(const bf16x8*)(wph + kt * 32);
        acc = MFMA(a, w, acc, 0, 0, 0);
      }
#pragma unroll
      for (int rr = 0; rr < 4; rr++) gh[mt * 16 + lk * 4 + rr][n] = acc[rr];
    }
    // --- hp n-shard: hp[all b][bk*16+lr] = h @ a1-slice (waves 0,1) ---
    if (wave < 2) {
      const u16* ah =
          hstep + (size_t)t * B * H + (size_t)(wave * 16 + lr) * H + lk * 8;
      const u16* bp = a1_bf + (size_t)(bk * 16 + lr) * 512 + lk * 8;
      f32x4 acc = {};
#pragma unroll
      for (int kt = 0; kt < 16; kt++) {
        bf16x8 a = *(const bf16x8*)(ah + kt * 32);
        bf16x8 w = *(const bf16x8*)(bp + kt * 32);
        acc = MFMA(a, w, acc, 0, 0, 0);
      }
#pragma unroll
      for (int rr = 0; rr < 4; rr++)
        hp2[wave * 16 + lk * 4 + rr][lr] = acc[rr];
    }
    __syncthreads();
    // publish hp shard (f32 pairs as u64)
    {
      u64 kp = 0;
      if (tid < 256) {
        int b = tid >> 3, ql = tid & 7;
        u64 pk = (u64)__float_as_uint(hp2[b][ql * 2]) |
                 ((u64)__float_as_uint(hp2[b][ql * 2 + 1]) << 32);
        kp = xstore64(
            (u64*)(hpstep + ((size_t)t * B + b) * 512 + bk * 16 + ql * 2), pk);
      }
      if (wave < 4) {
        asm volatile("" :: "v"(kp));
        asm volatile("s_waitcnt vmcnt(0)" ::: "memory");
      }
      __syncthreads();
      if (tid == 0) sstore(fps + bk * 16, (unsigned)(t + 1));
    }
    if (tid < 32) poll_bo(fps + tid * 16, (unsigned)(t + 1));
    __syncthreads();
    hps[tid] = hpstep[((size_t)t * B + bk) * 512 + tid];
    __syncthreads();
    // --- scores: wave w covers s in [w*16, w*16+16) ---
    {
      const int j0 = lane * 8;
      float hp8[8];
#pragma unroll
      for (int e = 0; e < 8; e++) hp8[e] = hps[j0 + e];
#pragma unroll 4
      for (int i = 0; i < 16; i++) {
        int s = wave * 16 + i;
        u16x8 ep = *(const u16x8*)&epart_bf[((size_t)bk * S + s) * H + j0];
        float a = 0.f;
#pragma unroll
        for (int e = 0; e < 8; e++) a += av8[e] * tanhf_(hp8[e] + bf2f(ep[e]));
#pragma unroll
        for (int o = 32; o; o >>= 1) a += __shfl_xor(a, o);
        if (lane == 0) sc[s] = (smask[s] == PAD_IDX) ? -1e10f : a;
      }
    }
    __syncthreads();
    if (tid < 64) {
      float v = fmaxf(sc[tid], sc[tid + 64]);
#pragma unroll
      for (int o = 32; o; o >>= 1) v = fmaxf(v, __shfl_xor(v, o));
      if (tid == 0) red[0] = v;
    }
    __syncthreads();
    if (tid < 64) {  // exp + sum merged
      float mx = red[0];
      float e0 = __expf(sc[tid] - mx), e1 = __expf(sc[tid + 64] - mx);
      sc[tid] = e0;
      sc[tid + 64] = e1;
      float v = e0 + e1;
#pragma unroll
      for (int o = 32; o; o >>= 1) v += __shfl_xor(v, o);
      if (tid == 0) red[1] = 1.f / v;
    }
    __syncthreads();
    {  // weighted partials: wave w owns s in [w*16, w*16+16)
      float acc8[8] = {};
      const int j0 = lane * 8;
#pragma unroll 4
      for (int i = 0; i < 16; i++) {
        int s = wave * 16 + i;
        float ps = sc[s];
        u16x8 ev = *(const u16x8*)&enc_bt_bf[((size_t)bk * S + s) * H + j0];
#pragma unroll
        for (int e = 0; e < 8; e++) acc8[e] += ps * bf2f(ev[e]);
      }
#pragma unroll
      for (int e = 0; e < 8; e++) buf[wave][j0 + e] = acc8[e];
    }
    __syncthreads();
    {  // finalize + publish w (own batch)
      u64 kp = 0;
      if (tid < 128) {
        float inv = red[1];
        int j0 = tid * 4;
        u16x4 o;
#pragma unroll
        for (int i = 0; i < 4; i++) {
          float wj = (buf[0][j0 + i] + buf[1][j0 + i] + buf[2][j0 + i] +
                      buf[3][j0 + i] + buf[4][j0 + i] + buf[5][j0 + i] +
                      buf[6][j0 + i] + buf[7][j0 + i]) *
                     inv;
          o[i] = f2bf(wj);
        }
        *(u16x4*)&xout_bf[((size_t)t * B + bk) * KOUT + H + j0] = o;
        u64 val = (u64)o[0] | ((u64)o[1] << 16) | ((u64)o[2] << 32) |
                  ((u64)o[3] << 48);
        kp = xstore(wstep + ((size_t)t * B + bk) * H + j0, val);
      }
      if (wave < 2) {
        asm volatile("" :: "v"(kp));
        asm volatile("s_waitcnt vmcnt(0)" ::: "memory");
      }
      __syncthreads();
      if (tid == 0) sstore(fws + bk * 16, (unsigned)(t + 1));
    }
    // --- gates_w: M=32, N=64, K=512 (B-frags in registers) ---
    if (tid < 32) poll_bo(fws + tid * 16, (unsigned)(t + 1));
    __syncthreads();
    {
      const u16* aw =
          wstep + (size_t)t * B * H + (size_t)(mt * 16 + lr) * H + lk * 8;
      f32x4 acc = {};
#pragma unroll
      for (int kt = 0; kt < 16; kt++) {
        bf16x8 a = *(const bf16x8*)(aw + kt * 32);
        acc = MFMA(a, wwf[kt], acc, 0, 0, 0);
      }
#pragma unroll
      for (int rr = 0; rr < 4; rr++) gw[mt * 16 + lk * 4 + rr][n] = acc[rr];
    }
    __syncthreads();
    {  // pointwise
      float gi = xv.x + gh[bq][jl * 4 + 0] + gw[bq][jl * 4 + 0];
      float gf = xv.y + gh[bq][jl * 4 + 1] + gw[bq][jl * 4 + 1];
      float gg = xv.z + gh[bq][jl * 4 + 2] + gw[bq][jl * 4 + 2];
      float go = xv.w + gh[bq][jl * 4 + 3] + gw[bq][jl * 4 + 3];
      float cn = sigm(gf) * c_s[tid] + sigm(gi) * tanh_(gg);
      c_s[tid] = cn;
      u16 h16 = f2bf(sigm(go) * tanh_(cn));
      hx[tid] = h16;
      xout_bf[((size_t)t * B + bq) * KOUT + bk * 16 + jl] = h16;
    }
    __syncthreads();
    {  // publish h slice
      u64 kp = 0;
      if (tid < 128) {
        int bb = tid >> 2, q = tid & 3;
        kp = xstore(hstep + (size_t)(t + 1) * B * H + (size_t)bb * H +
                        bk * 16 + q * 4,
                    pack4u(&hx[bb * 16 + q * 4]));
      }
      if (wave < 2) {
        asm volatile("" :: "v"(kp));
        asm volatile("s_waitcnt vmcnt(0)" ::: "memory");
      }
      __syncthreads();
      if (tid == 0) sstore(fhs + bk * 16, (unsigned)(t + 2));
    }
  }
}

// ---------------------------------------------------------------------------
extern "C" void kernel_launch(void* const* d_in, const int* in_sizes, int n_in,
                              void* d_out, int out_size, void* d_ws,
                              size_t ws_size, hipStream_t stream) {
  const int* src = (const int*)d_in[0];
  const int* trg = (const int*)d_in[2];
  const float* enc_emb = (const float*)d_in[3];
  const float* enc_wih = (const float*)d_in[4];
  const float* enc_whh = (const float*)d_in[5];
  const float* enc_bih = (const float*)d_in[6];
  const float* enc_bhh = (const float*)d_in[7];
  const float* fc_w = (const float*)d_in[8];
  const float* fc_b = (const float*)d_in[9];
  const float* dec_emb = (const float*)d_in[10];
  const float* attn_w = (const float*)d_in[11];
  const float* attn_b = (const float*)d_in[12];
  const float* attn_v = (const float*)d_in[13];
  const float* dec_wih = (const float*)d_in[14];
  const float* dec_whh = (const float*)d_in[15];
  const float* dec_bih = (const float*)d_in[16];
  const float* dec_bhh = (const float*)d_in[17];
  const float* out_w = (const float*)d_in[18];
  const float* out_b = (const float*)d_in[19];
  float* out = (float*)d_out;

  char* wp = (char*)d_ws;
  auto alloc = [&](size_t n) {
    char* p = wp;
    wp += (n + 255) & ~(size_t)255;
    return p;
  };
  u16* outw_bf = (u16*)alloc((size_t)V * KOUT * 2);        // 98.3 MB
  u16* wihenc_p = (u16*)alloc((size_t)H4 * H * 2);         // 2.1 MB
  u16* wihE_p = (u16*)alloc((size_t)H4 * H * 2);           // 2.1 MB
  u16* wenc_p = (u16*)alloc((size_t)H4 * H * 2);           // 2.1 MB
  u16* wdec_p = (u16*)alloc((size_t)H4 * 2 * H * 2);       // 8.4 MB
  u16* attnw2_bf = (u16*)alloc((size_t)H * H * 2);         // 0.5 MB
  u16* a1_bf = (u16*)alloc((size_t)H * H * 2);             // 0.5 MB
  u16* xemb_bf = (u16*)alloc((size_t)S * B * H * 2);       // 4.2 MB
  float* xih_p = (float*)alloc((size_t)S * B * H4 * 4);    // 33.6 MB
  u16* enc_bt_bf = (u16*)alloc((size_t)B * S * H * 2);     // 4.2 MB
  u16* epart_bf = (u16*)alloc((size_t)B * S * H * 2);      // 4.2 MB
  float* eih_p = (float*)alloc((size_t)MOUT * H4 * 4);     // 16.5 MB
  u16* xout_bf = (u16*)alloc((size_t)MOUT * KOUT * 2);     // 6.2 MB
  u16* hstep_enc = (u16*)alloc((size_t)(S + 1) * B * H * 2);  // 4.3 MB
  u16* hstep_dec = (u16*)alloc((size_t)T * B * H * 2);        // 2.1 MB
  u16* wstep = (u16*)alloc((size_t)TD * B * H * 2);           // 2.1 MB
  float* hpstep = (float*)alloc((size_t)TD * B * H * 4);      // 4.1 MB
  float* cbuf = (float*)alloc((size_t)B * H * 4);
  float* benc_p = (float*)alloc((size_t)H4 * 4);
  float* bdec_p = (float*)alloc((size_t)H4 * 4);
  unsigned* flags = (unsigned*)alloc(2048 * 4);
  unsigned* fes = flags;            // 32 slots x 16 u32
  unsigned* fhs = flags + 512;      // 32 slots x 16 u32
  unsigned* fws = flags + 1024;     // 32 slots x 16 u32
  unsigned* fps = flags + 1536;     // 32 slots x 16 u32

  dim3 blk(256);
  zero_f<<<dim3(256), blk, 0, stream>>>(out, (long)B * V);
  zero_u<<<dim3(8), blk, 0, stream>>>(flags, 2048);
  zero_u<<<dim3(32), blk, 0, stream>>>((unsigned*)hstep_enc, B * H / 2);
  // weight preparation (outw cast + eih GEMM moved into enc_fused)
  cast_perm<<<dim3(H / 256, H4), blk, 0, stream>>>(enc_wih, H, 0, wihenc_p);
  cast_perm<<<dim3(H / 256, H4), blk, 0, stream>>>(dec_wih, 2 * H, 0, wihE_p);
  cast_perm<<<dim3(H / 256, H4), blk, 0, stream>>>(enc_whh, H, 0, wenc_p);
  pack_wdec_p<<<dim3(4, H4), blk, 0, stream>>>(dec_wih, dec_whh, wdec_p);
  cast_bf<<<dim3(H / 256, H), blk, 0, stream>>>(attn_w, attnw2_bf, 2 * H, H, H);
  cast_bf<<<dim3(H / 256, H), blk, 0, stream>>>(attn_w, a1_bf, 2 * H, 0, H);
  bias_perm<<<dim3(H4 / 256), blk, 0, stream>>>(enc_bih, enc_bhh, benc_p);
  bias_perm<<<dim3(H4 / 256), blk, 0, stream>>>(dec_bih, dec_bhh, bdec_p);
  gather_src_emb<<<dim3(H / 256, S * B), blk, 0, stream>>>(src, enc_emb,
                                                           xemb_bf);
  gather_trg_emb<<<dim3(H / 256, MOUT), blk, 0, stream>>>(trg, dec_emb,
                                                          xout_bf);
  // xih GEMM (encoder consumes it from step 0)
  gemm_bt<<<dim3(H4 / 128, (S * B) / 128), blk, 0, stream>>>(
      xemb_bf, H, wihenc_p, H, xih_p, H4, benc_p, S * B, H, 0);
  // fused: encoder + eih GEMM + outw cast
  enc_fused<<<dim3(384), dim3(512), 0, stream>>>(
      fes, wenc_p, xih_p, hstep_enc, enc_bt_bf, cbuf, xout_bf + 2 * H, wihE_p,
      eih_p, bdec_p, out_w, outw_bf);
  // epart = enc_bt @ attn_w2^T + attn_b  (bf16 out, pre-dec)
  gemm_bt<<<dim3(H / 128, (B * S) / 128), blk, 0, stream>>>(
      enc_bt_bf, H, attnw2_bf, H, (float*)epart_bf, H, attn_b, B * S, H, 1);
  // persistent decoder (h_f = hstep_enc step S)
  dec_persist32<<<dim3(32), dim3(512), 0, stream>>>(
      fhs, fws, fps, fc_w, fc_b, wdec_p, a1_bf, attn_v, src,
      hstep_enc + (size_t)S * B * H, cbuf, epart_bf, enc_bt_bf, eih_p,
      hstep_dec, wstep, hpstep, xout_bf);
  // final logits GEMM
  gemm_bt<<<dim3(V / 128, (MOUT + 127) / 128), blk, 0, stream>>>(
      xout_bf, KOUT, outw_bf, KOUT, out + (size_t)B * V, V, out_b, MOUT, KOUT,
      0);
}

// Round 12
// 2815.260 us; speedup vs baseline: 7.5070x; 1.0422x over previous
//
#include <hip/hip_runtime.h>

typedef unsigned short u16;
typedef unsigned int u32;
typedef unsigned long long u64;
typedef __attribute__((ext_vector_type(8))) short bf16x8;
typedef __attribute__((ext_vector_type(8))) unsigned short u16x8;
typedef __attribute__((ext_vector_type(4))) unsigned short u16x4;
typedef __attribute__((ext_vector_type(4))) float f32x4;

#define DEVI static __device__ __forceinline__
#define MFMA __builtin_amdgcn_mfma_f32_16x16x32_bf16

constexpr int B = 32, S = 128, T = 64, H = 512, V = 32000;
constexpr int H4 = 4 * H;          // 2048
constexpr int TD = T - 1;          // 63 decoder steps
constexpr int MOUT = TD * B;       // 2016
constexpr int KOUT = 3 * H;        // 1536
constexpr int PAD_IDX = 1;

DEVI u16 f2bf(float f) {
  union { float f; unsigned u; } v; v.f = f;
  unsigned r = (v.u + 0x7fffu + ((v.u >> 16) & 1u)) >> 16;
  return (u16)r;
}
DEVI float bf2f(u16 h) {
  union { unsigned u; float f; } v; v.u = ((unsigned)h) << 16;
  return v.f;
}
DEVI float sigm(float x) { return 1.f / (1.f + __expf(-x)); }
DEVI float tanh_(float x) {
  float ax = fabsf(x);
  float e = __expf(-2.f * ax);
  float t = (1.f - e) / (1.f + e);
  return x < 0.f ? -t : t;
}
DEVI float tanhf_(float x) {
  float e = __expf(2.f * x);
  return 1.f - 2.f * __builtin_amdgcn_rcpf(e + 1.f);
}
DEVI int swz(int row, int k8) { return row * 32 + ((k8 ^ (row & 3)) << 3); }

DEVI u64 pack4u(const u16* p) {
  return (u64)p[0] | ((u64)p[1] << 16) | ((u64)p[2] << 32) | ((u64)p[3] << 48);
}
// data write-through to coherence point; returned old keeps vmcnt honest
DEVI u64 xstore(u16* p, u64 v) {
  return __hip_atomic_exchange((u64*)p, v, __ATOMIC_RELAXED,
                               __HIP_MEMORY_SCOPE_AGENT);
}
DEVI u64 xstore64(u64* p, u64 v) {
  return __hip_atomic_exchange(p, v, __ATOMIC_RELAXED,
                               __HIP_MEMORY_SCOPE_AGENT);
}
DEVI void sstore(unsigned* p, unsigned v) {
  __hip_atomic_exchange(p, v, __ATOMIC_RELAXED, __HIP_MEMORY_SCOPE_AGENT);
}
// poll with light backoff; loads only, 64B-strided slots
DEVI void poll_bo(unsigned* p, unsigned tgt) {
  int it = 0;
  long long t0 = (long long)__builtin_amdgcn_s_memrealtime();
  while (__hip_atomic_load(p, __ATOMIC_RELAXED, __HIP_MEMORY_SCOPE_AGENT) <
         tgt) {
    if (it < 4) {
      __builtin_amdgcn_s_sleep(1);
      it++;
    } else {
      __builtin_amdgcn_s_sleep(4);
    }
    if ((long long)__builtin_amdgcn_s_memrealtime() - t0 > 20000000ll) break;
  }
}
// slow poll for coarse gating (GEMM blocks): ~0.5us quantum
DEVI void poll_slow(unsigned* p, unsigned tgt) {
  long long t0 = (long long)__builtin_amdgcn_s_memrealtime();
  while (__hip_atomic_load(p, __ATOMIC_RELAXED, __HIP_MEMORY_SCOPE_AGENT) <
         tgt) {
    __builtin_amdgcn_s_sleep(16);
    if ((long long)__builtin_amdgcn_s_memrealtime() - t0 > 20000000ll) break;
  }
}

// ---------------- bf16 MFMA GEMM (256-thr standalone) ----------------------
__global__ __launch_bounds__(256) void gemm_bt(
    const u16* __restrict__ A, int lda,
    const u16* __restrict__ Bt, int ldb,
    float* __restrict__ C, int ldc,
    const float* __restrict__ bias, int M, int K, int bf16out) {
  __shared__ u16 As[128 * 32], Bs[128 * 32];
  const int tid = threadIdx.x;
  const int m0 = blockIdx.y * 128, n0 = blockIdx.x * 128;
  const int lane = tid & 63, w = tid >> 6, wm = w >> 1, wn = w & 1;
  const int lr = lane & 15, lk = lane >> 4;
  f32x4 acc[4][4] = {};
  const int r = tid >> 1, cc = (tid & 1) * 16, k8b = (tid & 1) * 2;

  for (int k0 = 0; k0 < K; k0 += 32) {
    {
      long gr = m0 + r;
      u16x8 v0 = {}, v1 = {};
      if (gr < M) {
        const u16* s = A + gr * (long)lda + k0 + cc;
        v0 = *(const u16x8*)s;
        v1 = *(const u16x8*)(s + 8);
      }
      *(u16x8*)&As[swz(r, k8b)] = v0;
      *(u16x8*)&As[swz(r, k8b + 1)] = v1;
    }
    {
      const u16* s = Bt + (long)(n0 + r) * ldb + k0 + cc;
      u16x8 v0 = *(const u16x8*)s;
      u16x8 v1 = *(const u16x8*)(s + 8);
      *(u16x8*)&Bs[swz(r, k8b)] = v0;
      *(u16x8*)&Bs[swz(r, k8b + 1)] = v1;
    }
    __syncthreads();
    bf16x8 af[4], bfr[4];
#pragma unroll
    for (int mi = 0; mi < 4; mi++)
      af[mi] = *(const bf16x8*)&As[swz(wm * 64 + mi * 16 + lr, lk)];
#pragma unroll
    for (int ni = 0; ni < 4; ni++)
      bfr[ni] = *(const bf16x8*)&Bs[swz(wn * 64 + ni * 16 + lr, lk)];
#pragma unroll
    for (int mi = 0; mi < 4; mi++)
#pragma unroll
      for (int ni = 0; ni < 4; ni++)
        acc[mi][ni] = MFMA(af[mi], bfr[ni], acc[mi][ni], 0, 0, 0);
    __syncthreads();
  }
#pragma unroll
  for (int ni = 0; ni < 4; ni++) {
    int col = n0 + wn * 64 + ni * 16 + lr;
    float bs = bias ? bias[col] : 0.f;
#pragma unroll
    for (int mi = 0; mi < 4; mi++) {
#pragma unroll
      for (int rr = 0; rr < 4; rr++) {
        long row = m0 + wm * 64 + mi * 16 + lk * 4 + rr;
        if (row < M) {
          float v = acc[mi][ni][rr] + bs;
          if (bf16out)
            ((u16*)C)[row * (long)ldc + col] = f2bf(v);
          else
            C[row * (long)ldc + col] = v;
        }
      }
    }
  }
}

// 512-thread tile variant (threads 256..511 idle but join barriers)
DEVI void gemm_tile512(const u16* A, int lda, const u16* Bt, int ldb,
                       float* C, int ldc, const float* bias, int M, int K,
                       int mt, int nt) {
  __shared__ u16 As[128 * 32], Bs[128 * 32];
  const int tid = threadIdx.x;
  const bool act = tid < 256;
  const int m0 = mt * 128, n0 = nt * 128;
  const int lane = tid & 63, w = tid >> 6, wm = (w >> 1) & 1, wn = w & 1;
  const int lr = lane & 15, lk = lane >> 4;
  f32x4 acc[4][4] = {};
  const int r = (tid >> 1) & 127, cc = (tid & 1) * 16, k8b = (tid & 1) * 2;

  for (int k0 = 0; k0 < K; k0 += 32) {
    if (act) {
      {
        long gr = m0 + r;
        u16x8 v0 = {}, v1 = {};
        if (gr < M) {
          const u16* s = A + gr * (long)lda + k0 + cc;
          v0 = *(const u16x8*)s;
          v1 = *(const u16x8*)(s + 8);
        }
        *(u16x8*)&As[swz(r, k8b)] = v0;
        *(u16x8*)&As[swz(r, k8b + 1)] = v1;
      }
      {
        const u16* s = Bt + (long)(n0 + r) * ldb + k0 + cc;
        u16x8 v0 = *(const u16x8*)s;
        u16x8 v1 = *(const u16x8*)(s + 8);
        *(u16x8*)&Bs[swz(r, k8b)] = v0;
        *(u16x8*)&Bs[swz(r, k8b + 1)] = v1;
      }
    }
    __syncthreads();
    if (act) {
      bf16x8 af[4], bfr[4];
#pragma unroll
      for (int mi = 0; mi < 4; mi++)
        af[mi] = *(const bf16x8*)&As[swz(wm * 64 + mi * 16 + lr, lk)];
#pragma unroll
      for (int ni = 0; ni < 4; ni++)
        bfr[ni] = *(const bf16x8*)&Bs[swz(wn * 64 + ni * 16 + lr, lk)];
#pragma unroll
      for (int mi = 0; mi < 4; mi++)
#pragma unroll
        for (int ni = 0; ni < 4; ni++)
          acc[mi][ni] = MFMA(af[mi], bfr[ni], acc[mi][ni], 0, 0, 0);
    }
    __syncthreads();
  }
  if (act) {
#pragma unroll
    for (int ni = 0; ni < 4; ni++) {
      int col = n0 + wn * 64 + ni * 16 + lr;
      float bs = bias ? bias[col] : 0.f;
#pragma unroll
      for (int mi = 0; mi < 4; mi++) {
#pragma unroll
        for (int rr = 0; rr < 4; rr++) {
          long row = m0 + wm * 64 + mi * 16 + lk * 4 + rr;
          if (row < M) C[row * (long)ldc + col] = acc[mi][ni][rr] + bs;
        }
      }
    }
  }
}

// ---------------- helpers ---------------------------------------------------
__global__ void zero_f(float* p, long n) {
  long i = (long)blockIdx.x * 256 + threadIdx.x;
  long st = (long)gridDim.x * 256;
  for (; i < n; i += st) p[i] = 0.f;
}

__global__ void zero_u(unsigned* p, int n) {
  int i = blockIdx.x * 256 + threadIdx.x;
  if (i < n) p[i] = 0u;
}

__global__ void cast_bf(const float* __restrict__ src, u16* __restrict__ dst,
                        int ld, int off, int Csz) {
  long row = blockIdx.y;
  int col = blockIdx.x * 256 + threadIdx.x;
  dst[row * Csz + col] = f2bf(src[row * ld + off + col]);
}

// permuted-row cast: dst row n' = src row (g*H + jH), n' = jH*4 + g
__global__ void cast_perm(const float* __restrict__ src, int ld, int off,
                          u16* __restrict__ dst) {
  int np = blockIdx.y;
  int c = blockIdx.x * 256 + threadIdx.x;
  int g = np & 3, jH = np >> 2;
  dst[(size_t)np * H + c] = f2bf(src[(size_t)(g * H + jH) * ld + off + c]);
}

// wdec_p row r = j*4+g, cols [0:512)=wih weighted-part, [512:1024)=whh
__global__ void pack_wdec_p(const float* __restrict__ wih,
                            const float* __restrict__ whh,
                            u16* __restrict__ dst) {
  int r = blockIdx.y;
  int k = blockIdx.x * 256 + threadIdx.x;
  int g = r & 3, j = r >> 2;
  int srow = g * H + j;
  float v = (k < 512) ? wih[(size_t)srow * (2 * H) + 512 + k]
                      : whh[(size_t)srow * H + (k - 512)];
  dst[(size_t)r * 1024 + k] = f2bf(v);
}

__global__ void bias_perm(const float* __restrict__ a,
                          const float* __restrict__ b, float* __restrict__ o) {
  int np = blockIdx.x * 256 + threadIdx.x;
  int g = np & 3, jH = np >> 2;
  int r = g * H + jH;
  o[np] = a[r] + b[r];
}

__global__ void gather_src_emb(const int* __restrict__ src,
                               const float* __restrict__ emb,
                               u16* __restrict__ dst) {
  int row = blockIdx.y;           // row = t*B + b
  int t = row >> 5, b = row & 31;
  int c = blockIdx.x * 256 + threadIdx.x;
  int tok = src[b * S + t];
  dst[(long)row * H + c] = f2bf(emb[(long)tok * H + c]);
}

__global__ void gather_trg_emb(const int* __restrict__ trg,
                               const float* __restrict__ emb,
                               u16* __restrict__ xout) {
  int row = blockIdx.y;           // row = t*B + b, t < 63
  int t = row >> 5, b = row & 31;
  int c = blockIdx.x * 256 + threadIdx.x;
  int tok = trg[b * T + t];
  xout[(long)row * KOUT + 2 * H + c] = f2bf(emb[(long)tok * H + c]);
}

// ---------------- fused encoder launch --------------------------------------
// blocks 0..31: persistent encoder. blocks 32..287: eih GEMM tiles.
// blocks 288..383: outw cast. All co-resident (2/CU at 512 threads).
__global__ __launch_bounds__(512) void enc_fused(
    unsigned* fes, const u16* __restrict__ wenc_p,
    const float* __restrict__ xih_p, u16* hstep, u16* enc_bt_bf, float* cbuf,
    const u16* __restrict__ xoute, const u16* __restrict__ wihE_p,
    float* __restrict__ eih_p, const float* __restrict__ bdec_p,
    const float* __restrict__ out_w, u16* __restrict__ outw_bf) {
  const int bk = blockIdx.x;
  if (bk >= 288) {  // outw cast, grid-stride
    long i = (long)(bk - 288) * 512 + threadIdx.x;
    const long n4 = (long)V * KOUT / 4, st = 96L * 512;
    for (; i < n4; i += st) {
      float4 v = ((const float4*)out_w)[i];
      u16x4 o;
      o[0] = f2bf(v.x); o[1] = f2bf(v.y); o[2] = f2bf(v.z); o[3] = f2bf(v.w);
      *(u16x4*)&outw_bf[i * 4] = o;
    }
    return;
  }
  if (bk >= 32) {  // eih = xout_e @ wihE_p^T + bdec_p
    int job = bk - 32, mt = job >> 4, nt = job & 15;
    gemm_tile512(xoute, KOUT, wihE_p, H, eih_p, H4, bdec_p, MOUT, H, mt, nt);
    return;
  }
  // ---- persistent encoder block ----
  __shared__ float gs[32][64];
  __shared__ float c_s[512];
  __shared__ u16 hx[512];
  const int tid = threadIdx.x;
  const int wave = tid >> 6, lane = tid & 63;
  const int lr = lane & 15, lk = lane >> 4;
  const int bq = tid >> 4, jl = tid & 15;
  c_s[tid] = 0.f;
  const int mt = wave & 1, nt = wave >> 1;
  const int n = nt * 16 + lr;
  bf16x8 wf[16];
  {
    const u16* wp = wenc_p + (size_t)(bk * 64 + n) * 512 + lk * 8;
#pragma unroll
    for (int kt = 0; kt < 16; kt++) wf[kt] = *(const bf16x8*)(wp + kt * 32);
  }
  for (int t = 0; t < S; t++) {
    if (t > 0 && tid < 32) poll_bo(fes + tid * 16, (unsigned)t);
    __syncthreads();
    float4 xv = *(const float4*)(xih_p + ((size_t)t * B + bq) * H4 +
                                 (bk * 16 + jl) * 4);
    {
      const u16* ab =
          hstep + (size_t)t * B * H + (size_t)(mt * 16 + lr) * H + lk * 8;
      f32x4 acc = {};
#pragma unroll
      for (int kt = 0; kt < 16; kt++) {
        bf16x8 a = *(const bf16x8*)(ab + kt * 32);
        acc = MFMA(a, wf[kt], acc, 0, 0, 0);
      }
#pragma unroll
      for (int rr = 0; rr < 4; rr++) gs[mt * 16 + lk * 4 + rr][n] = acc[rr];
    }
    __syncthreads();
    {
      float gi = xv.x + gs[bq][jl * 4 + 0];
      float gf = xv.y + gs[bq][jl * 4 + 1];
      float gg = xv.z + gs[bq][jl * 4 + 2];
      float go = xv.w + gs[bq][jl * 4 + 3];
      float cn = sigm(gf) * c_s[tid] + sigm(gi) * tanh_(gg);
      c_s[tid] = cn;
      u16 h16 = f2bf(sigm(go) * tanh_(cn));
      hx[tid] = h16;
      enc_bt_bf[((size_t)bq * S + t) * H + bk * 16 + jl] = h16;
    }
    __syncthreads();
    u64 kp = 0;
    if (tid < 128) {
      int bb = tid >> 2, q = tid & 3;
      kp = xstore(hstep + (size_t)(t + 1) * B * H + (size_t)bb * H + bk * 16 +
                      q * 4,
                  pack4u(&hx[bb * 16 + q * 4]));
    }
    if (wave < 2) {
      asm volatile("" :: "v"(kp));
      asm volatile("s_waitcnt vmcnt(0)" ::: "memory");
    }
    __syncthreads();
    if (tid == 0) sstore(fes + bk * 16, (unsigned)(t + 1));
  }
  cbuf[bq * H + bk * 16 + jl] = c_s[tid];
}

// ---------------- fused decoder + final GEMM: 256 blocks x 512 -------------
// blocks 0..31: persistent decoder (batch bk attn + j-col LSTM shard + hp
// n-shard). blocks 32..255: final logits GEMM tiles, flag-gated on fhs.
__global__ __launch_bounds__(512) void dec_fused(
    unsigned* fhs, unsigned* fws, unsigned* fps, const float* __restrict__ fc_w,
    const float* __restrict__ fc_b, const u16* __restrict__ wdec_p,
    const u16* __restrict__ a1_bf, const float* __restrict__ attn_v,
    const int* __restrict__ src, const u16* __restrict__ hf_bf,
    const float* __restrict__ cbuf, const u16* __restrict__ epart_bf,
    const u16* __restrict__ enc_bt_bf, const float* __restrict__ eih_p,
    u16* hstep, u16* wstep, float* hpstep, u16* __restrict__ xout_bf,
    const u16* __restrict__ outw_bf, const float* __restrict__ out_b,
    float* __restrict__ out) {
  const int tid = threadIdx.x, bk = blockIdx.x;
  if (bk >= 32) {
    // ---- final GEMM tiles: logits[2016,32000] = xout @ outw^T + out_b ----
    const int g = bk - 32;            // 0..223
    for (int j = g; j < 16 * 250; j += 224) {
      int mt = j / 250, nt = j % 250;
      int tmax = mt * 4 + 3;
      unsigned tgt = (unsigned)((tmax > TD - 1 ? TD - 1 : tmax) + 2);
      if (tid < 32) poll_slow(fhs + tid * 16, tgt);
      __syncthreads();
      gemm_tile512(xout_bf, KOUT, outw_bf, KOUT, out + (size_t)B * V, V,
                   out_b, MOUT, KOUT, mt, nt);
    }
    return;
  }
  // ---- persistent decoder block ----
  __shared__ float buf[8][512];   // weighted partials
  __shared__ float hps[512];
  __shared__ float hp2[32][16];
  __shared__ float gh[32][64];
  __shared__ float gw[32][64];
  __shared__ float sc[128], red[2];
  __shared__ int smask[128];
  __shared__ float c_s[512];
  __shared__ u16 hx[512];
  const int wave = tid >> 6, lane = tid & 63;
  const int lr = lane & 15, lk = lane >> 4;
  const int bq = tid >> 4, jl = tid & 15;
  c_s[tid] = cbuf[bq * H + bk * 16 + jl];
  if (tid < 128) smask[tid] = src[bk * S + tid];
  float av8[8];
#pragma unroll
  for (int e = 0; e < 8; e++) av8[e] = attn_v[lane * 8 + e];
  // fc: hidden = tanh(hf @ fc_w^T + fc_b) -> h[0] slice (waves 0,1)
  if (wave < 2) {
    const u16* ab = hf_bf + (size_t)(wave * 16 + lr) * H + lk * 8;
    const float* frow = fc_w + (size_t)(bk * 16 + lr) * H + lk * 8;
    f32x4 acc = {};
#pragma unroll
    for (int kt = 0; kt < 16; kt++) {
      bf16x8 a = *(const bf16x8*)(ab + kt * 32);
      bf16x8 w;
#pragma unroll
      for (int e = 0; e < 8; e++) w[e] = (short)f2bf(frow[kt * 32 + e]);
      acc = MFMA(a, w, acc, 0, 0, 0);
    }
    float bs = fc_b[bk * 16 + lr];
#pragma unroll
    for (int rr = 0; rr < 4; rr++)
      hx[(wave * 16 + lk * 4 + rr) * 16 + lr] = f2bf(tanh_(acc[rr] + bs));
  }
  __syncthreads();
  {
    u64 kp = 0;
    if (tid < 128) {
      int bb = tid >> 2, q = tid & 3;
      kp = xstore(hstep + (size_t)bb * H + bk * 16 + q * 4,
                  pack4u(&hx[bb * 16 + q * 4]));
    }
    if (wave < 2) {
      asm volatile("" :: "v"(kp));
      asm volatile("s_waitcnt vmcnt(0)" ::: "memory");
    }
    __syncthreads();
    if (tid == 0) sstore(fhs + bk * 16, 1u);
  }
  // gate weight slices; register-cache the w-part (post-poll path)
  const int mt = wave & 1, nt = wave >> 1;
  const int n = nt * 16 + lr;
  const u16* wpw = wdec_p + (size_t)(bk * 64 + n) * 1024 + lk * 8;
  const u16* wph = wpw + 512;
  bf16x8 wwf[16];
#pragma unroll
  for (int kt = 0; kt < 16; kt++) wwf[kt] = *(const bf16x8*)(wpw + kt * 32);
  // ---- time loop ----
  for (int t = 0; t < TD; t++) {
    if (tid < 32) poll_bo(fhs + tid * 16, (unsigned)(t + 1));
    __syncthreads();
    float4 xv = *(const float4*)(eih_p + ((size_t)t * B + bq) * H4 +
                                 (bk * 16 + jl) * 4);
    // --- gates_h (all waves) ---
    {
      const u16* ah =
          hstep + (size_t)t * B * H + (size_t)(mt * 16 + lr) * H + lk * 8;
      f32x4 acc = {};
#pragma unroll
      for (int kt = 0; kt < 16; kt++) {
        bf16x8 a = *(const bf16x8*)(ah + kt * 32);
        bf16x8 w = *(const bf16x8*)(wph + kt * 32);
        acc = MFMA(a, w, acc, 0, 0, 0);
      }
#pragma unroll
      for (int rr = 0; rr < 4; rr++) gh[mt * 16 + lk * 4 + rr][n] = acc[rr];
    }
    // --- hp n-shard: hp[all b][bk*16+lr] = h @ a1-slice (waves 0,1) ---
    if (wave < 2) {
      const u16* ah =
          hstep + (size_t)t * B * H + (size_t)(wave * 16 + lr) * H + lk * 8;
      const u16* bp = a1_bf + (size_t)(bk * 16 + lr) * 512 + lk * 8;
      f32x4 acc = {};
#pragma unroll
      for (int kt = 0; kt < 16; kt++) {
        bf16x8 a = *(const bf16x8*)(ah + kt * 32);
        bf16x8 w = *(const bf16x8*)(bp + kt * 32);
        acc = MFMA(a, w, acc, 0, 0, 0);
      }
#pragma unroll
      for (int rr = 0; rr < 4; rr++)
        hp2[wave * 16 + lk * 4 + rr][lr] = acc[rr];
    }
    __syncthreads();
    // publish hp shard (f32 pairs as u64)
    {
      u64 kp = 0;
      if (tid < 256) {
        int b = tid >> 3, ql = tid & 7;
        u64 pk = (u64)__float_as_uint(hp2[b][ql * 2]) |
                 ((u64)__float_as_uint(hp2[b][ql * 2 + 1]) << 32);
        kp = xstore64(
            (u64*)(hpstep + ((size_t)t * B + b) * 512 + bk * 16 + ql * 2), pk);
      }
      if (wave < 4) {
        asm volatile("" :: "v"(kp));
        asm volatile("s_waitcnt vmcnt(0)" ::: "memory");
      }
      __syncthreads();
      if (tid == 0) sstore(fps + bk * 16, (unsigned)(t + 1));
    }
    if (tid < 32) poll_bo(fps + tid * 16, (unsigned)(t + 1));
    __syncthreads();
    hps[tid] = hpstep[((size_t)t * B + bk) * 512 + tid];
    __syncthreads();
    // --- scores: wave w covers s in [w*16, w*16+16) ---
    {
      const int j0 = lane * 8;
      float hp8[8];
#pragma unroll
      for (int e = 0; e < 8; e++) hp8[e] = hps[j0 + e];
#pragma unroll 4
      for (int i = 0; i < 16; i++) {
        int s = wave * 16 + i;
        u16x8 ep = *(const u16x8*)&epart_bf[((size_t)bk * S + s) * H + j0];
        float a = 0.f;
#pragma unroll
        for (int e = 0; e < 8; e++) a += av8[e] * tanhf_(hp8[e] + bf2f(ep[e]));
#pragma unroll
        for (int o = 32; o; o >>= 1) a += __shfl_xor(a, o);
        if (lane == 0) sc[s] = (smask[s] == PAD_IDX) ? -1e10f : a;
      }
    }
    __syncthreads();
    // softmax without max-subtraction (scores bounded by sum|v| ~ 20)
    if (tid < 64) {
      float e0 = __expf(sc[tid]), e1 = __expf(sc[tid + 64]);
      sc[tid] = e0;
      sc[tid + 64] = e1;
      float v = e0 + e1;
#pragma unroll
      for (int o = 32; o; o >>= 1) v += __shfl_xor(v, o);
      if (tid == 0) red[1] = 1.f / v;
    }
    __syncthreads();
    {  // weighted partials: wave w owns s in [w*16, w*16+16)
      float acc8[8] = {};
      const int j0 = lane * 8;
#pragma unroll 4
      for (int i = 0; i < 16; i++) {
        int s = wave * 16 + i;
        float ps = sc[s];
        u16x8 ev = *(const u16x8*)&enc_bt_bf[((size_t)bk * S + s) * H + j0];
#pragma unroll
        for (int e = 0; e < 8; e++) acc8[e] += ps * bf2f(ev[e]);
      }
#pragma unroll
      for (int e = 0; e < 8; e++) buf[wave][j0 + e] = acc8[e];
    }
    __syncthreads();
    {  // finalize + publish w (own batch); xout w write is write-through too
      u64 kp = 0;
      if (tid < 128) {
        float inv = red[1];
        int j0 = tid * 4;
        u16x4 o;
#pragma unroll
        for (int i = 0; i < 4; i++) {
          float wj = (buf[0][j0 + i] + buf[1][j0 + i] + buf[2][j0 + i] +
                      buf[3][j0 + i] + buf[4][j0 + i] + buf[5][j0 + i] +
                      buf[6][j0 + i] + buf[7][j0 + i]) *
                     inv;
          o[i] = f2bf(wj);
        }
        u64 val = (u64)o[0] | ((u64)o[1] << 16) | ((u64)o[2] << 32) |
                  ((u64)o[3] << 48);
        kp = xstore(wstep + ((size_t)t * B + bk) * H + j0, val);
        kp ^= xstore(&xout_bf[((size_t)t * B + bk) * KOUT + H + j0], val);
      }
      if (wave < 2) {
        asm volatile("" :: "v"(kp));
        asm volatile("s_waitcnt vmcnt(0)" ::: "memory");
      }
      __syncthreads();
      if (tid == 0) sstore(fws + bk * 16, (unsigned)(t + 1));
    }
    // --- gates_w: M=32, N=64, K=512 (B-frags in registers) ---
    if (tid < 32) poll_bo(fws + tid * 16, (unsigned)(t + 1));
    __syncthreads();
    {
      const u16* aw =
          wstep + (size_t)t * B * H + (size_t)(mt * 16 + lr) * H + lk * 8;
      f32x4 acc = {};
#pragma unroll
      for (int kt = 0; kt < 16; kt++) {
        bf16x8 a = *(const bf16x8*)(aw + kt * 32);
        acc = MFMA(a, wwf[kt], acc, 0, 0, 0);
      }
#pragma unroll
      for (int rr = 0; rr < 4; rr++) gw[mt * 16 + lk * 4 + rr][n] = acc[rr];
    }
    __syncthreads();
    {  // pointwise
      float gi = xv.x + gh[bq][jl * 4 + 0] + gw[bq][jl * 4 + 0];
      float gf = xv.y + gh[bq][jl * 4 + 1] + gw[bq][jl * 4 + 1];
      float gg = xv.z + gh[bq][jl * 4 + 2] + gw[bq][jl * 4 + 2];
      float go = xv.w + gh[bq][jl * 4 + 3] + gw[bq][jl * 4 + 3];
      float cn = sigm(gf) * c_s[tid] + sigm(gi) * tanh_(gg);
      c_s[tid] = cn;
      u16 h16 = f2bf(sigm(go) * tanh_(cn));
      hx[tid] = h16;
    }
    __syncthreads();
    {  // publish h slice (hstep + xout, both write-through, one vmcnt)
      u64 kp = 0;
      if (tid < 128) {
        int bb = tid >> 2, q = tid & 3;
        u64 hv = pack4u(&hx[bb * 16 + q * 4]);
        kp = xstore(hstep + (size_t)(t + 1) * B * H + (size_t)bb * H +
                        bk * 16 + q * 4,
                    hv);
        kp ^= xstore(&xout_bf[((size_t)t * B + bb) * KOUT + bk * 16 + q * 4],
                     hv);
      }
      if (wave < 2) {
        asm volatile("" :: "v"(kp));
        asm volatile("s_waitcnt vmcnt(0)" ::: "memory");
      }
      __syncthreads();
      if (tid == 0) sstore(fhs + bk * 16, (unsigned)(t + 2));
    }
  }
}

// ---------------------------------------------------------------------------
extern "C" void kernel_launch(void* const* d_in, const int* in_sizes, int n_in,
                              void* d_out, int out_size, void* d_ws,
                              size_t ws_size, hipStream_t stream) {
  const int* src = (const int*)d_in[0];
  const int* trg = (const int*)d_in[2];
  const float* enc_emb = (const float*)d_in[3];
  const float* enc_wih = (const float*)d_in[4];
  const float* enc_whh = (const float*)d_in[5];
  const float* enc_bih = (const float*)d_in[6];
  const float* enc_bhh = (const float*)d_in[7];
  const float* fc_w = (const float*)d_in[8];
  const float* fc_b = (const float*)d_in[9];
  const float* dec_emb = (const float*)d_in[10];
  const float* attn_w = (const float*)d_in[11];
  const float* attn_b = (const float*)d_in[12];
  const float* attn_v = (const float*)d_in[13];
  const float* dec_wih = (const float*)d_in[14];
  const float* dec_whh = (const float*)d_in[15];
  const float* dec_bih = (const float*)d_in[16];
  const float* dec_bhh = (const float*)d_in[17];
  const float* out_w = (const float*)d_in[18];
  const float* out_b = (const float*)d_in[19];
  float* out = (float*)d_out;

  char* wp = (char*)d_ws;
  auto alloc = [&](size_t n) {
    char* p = wp;
    wp += (n + 255) & ~(size_t)255;
    return p;
  };
  u16* outw_bf = (u16*)alloc((size_t)V * KOUT * 2);        // 98.3 MB
  u16* wihenc_p = (u16*)alloc((size_t)H4 * H * 2);         // 2.1 MB
  u16* wihE_p = (u16*)alloc((size_t)H4 * H * 2);           // 2.1 MB
  u16* wenc_p = (u16*)alloc((size_t)H4 * H * 2);           // 2.1 MB
  u16* wdec_p = (u16*)alloc((size_t)H4 * 2 * H * 2);       // 8.4 MB
  u16* attnw2_bf = (u16*)alloc((size_t)H * H * 2);         // 0.5 MB
  u16* a1_bf = (u16*)alloc((size_t)H * H * 2);             // 0.5 MB
  u16* xemb_bf = (u16*)alloc((size_t)S * B * H * 2);       // 4.2 MB
  float* xih_p = (float*)alloc((size_t)S * B * H4 * 4);    // 33.6 MB
  u16* enc_bt_bf = (u16*)alloc((size_t)B * S * H * 2);     // 4.2 MB
  u16* epart_bf = (u16*)alloc((size_t)B * S * H * 2);      // 4.2 MB
  float* eih_p = (float*)alloc((size_t)MOUT * H4 * 4);     // 16.5 MB
  u16* xout_bf = (u16*)alloc((size_t)MOUT * KOUT * 2);     // 6.2 MB
  u16* hstep_enc = (u16*)alloc((size_t)(S + 1) * B * H * 2);  // 4.3 MB
  u16* hstep_dec = (u16*)alloc((size_t)T * B * H * 2);        // 2.1 MB
  u16* wstep = (u16*)alloc((size_t)TD * B * H * 2);           // 2.1 MB
  float* hpstep = (float*)alloc((size_t)TD * B * H * 4);      // 4.1 MB
  float* cbuf = (float*)alloc((size_t)B * H * 4);
  float* benc_p = (float*)alloc((size_t)H4 * 4);
  float* bdec_p = (float*)alloc((size_t)H4 * 4);
  unsigned* flags = (unsigned*)alloc(2048 * 4);
  unsigned* fes = flags;            // 32 slots x 16 u32
  unsigned* fhs = flags + 512;      // 32 slots x 16 u32
  unsigned* fws = flags + 1024;     // 32 slots x 16 u32
  unsigned* fps = flags + 1536;     // 32 slots x 16 u32

  dim3 blk(256);
  zero_f<<<dim3(256), blk, 0, stream>>>(out, (long)B * V);
  zero_u<<<dim3(8), blk, 0, stream>>>(flags, 2048);
  zero_u<<<dim3(32), blk, 0, stream>>>((unsigned*)hstep_enc, B * H / 2);
  // weight preparation (outw cast + eih GEMM fused into enc launch)
  cast_perm<<<dim3(H / 256, H4), blk, 0, stream>>>(enc_wih, H, 0, wihenc_p);
  cast_perm<<<dim3(H / 256, H4), blk, 0, stream>>>(dec_wih, 2 * H, 0, wihE_p);
  cast_perm<<<dim3(H / 256, H4), blk, 0, stream>>>(enc_whh, H, 0, wenc_p);
  pack_wdec_p<<<dim3(4, H4), blk, 0, stream>>>(dec_wih, dec_whh, wdec_p);
  cast_bf<<<dim3(H / 256, H), blk, 0, stream>>>(attn_w, attnw2_bf, 2 * H, H, H);
  cast_bf<<<dim3(H / 256, H), blk, 0, stream>>>(attn_w, a1_bf, 2 * H, 0, H);
  bias_perm<<<dim3(H4 / 256), blk, 0, stream>>>(enc_bih, enc_bhh, benc_p);
  bias_perm<<<dim3(H4 / 256), blk, 0, stream>>>(dec_bih, dec_bhh, bdec_p);
  gather_src_emb<<<dim3(H / 256, S * B), blk, 0, stream>>>(src, enc_emb,
                                                           xemb_bf);
  gather_trg_emb<<<dim3(H / 256, MOUT), blk, 0, stream>>>(trg, dec_emb,
                                                          xout_bf);
  // xih GEMM (encoder consumes it from step 0)
  gemm_bt<<<dim3(H4 / 128, (S * B) / 128), blk, 0, stream>>>(
      xemb_bf, H, wihenc_p, H, xih_p, H4, benc_p, S * B, H, 0);
  // fused: encoder + eih GEMM + outw cast
  enc_fused<<<dim3(384), dim3(512), 0, stream>>>(
      fes, wenc_p, xih_p, hstep_enc, enc_bt_bf, cbuf, xout_bf + 2 * H, wihE_p,
      eih_p, bdec_p, out_w, outw_bf);
  // epart = enc_bt @ attn_w2^T + attn_b  (bf16 out, pre-dec)
  gemm_bt<<<dim3(H / 128, (B * S) / 128), blk, 0, stream>>>(
      enc_bt_bf, H, attnw2_bf, H, (float*)epart_bf, H, attn_b, B * S, H, 1);
  // fused: persistent decoder + final logits GEMM (flag-gated overlap)
  dec_fused<<<dim3(256), dim3(512), 0, stream>>>(
      fhs, fws, fps, fc_w, fc_b, wdec_p, a1_bf, attn_v, src,
      hstep_enc + (size_t)S * B * H, cbuf, epart_bf, enc_bt_bf, eih_p,
      hstep_dec, wstep, hpstep, xout_bf, outw_bf, out_b, out);
}